// Round 3
// baseline (1380.073 us; speedup 1.0000x reference)
//
#include <hip/hip_runtime.h>

typedef __attribute__((ext_vector_type(8))) short short8;
typedef __attribute__((ext_vector_type(4))) float f32x4;

__device__ __forceinline__ float silu_f(float x) { return x / (1.0f + __expf(-x)); }

__device__ __forceinline__ unsigned short f2bf(float x) {
  unsigned u = __float_as_uint(x);
  u += 0x7FFFu + ((u >> 16) & 1u);
  return (unsigned short)(u >> 16);
}

// raw barrier: make my LDS writes visible, sync, but do NOT drain vmcnt
#define TSYNC() do { asm volatile("s_waitcnt lgkmcnt(0)" ::: "memory"); \
                     __builtin_amdgcn_s_barrier(); \
                     asm volatile("" ::: "memory"); } while (0)

// ---------------- generic f32 row-tile GEMM: C = act(A @ W + b) ----------------
template<int TN, int ACT>
__global__ __launch_bounds__(256)
void gemm_rowtile(const float* A, const float* __restrict__ W,
                  const float* __restrict__ bias, float* C, int M, int K)
{
  constexpr int NC = TN / 64;
  __shared__ float As[64][17];
  __shared__ float Bs[16][TN + 4];
  const int tid = threadIdx.x;
  const int tx = tid & 15, ty = tid >> 4;
  const int row0 = blockIdx.x * 64;

  float acc[NC][4][4];
#pragma unroll
  for (int c = 0; c < NC; c++)
#pragma unroll
    for (int i = 0; i < 4; i++)
#pragma unroll
      for (int j = 0; j < 4; j++) acc[c][i][j] = 0.f;

  for (int kc = 0; kc < K; kc += 16) {
#pragma unroll
    for (int i = 0; i < 4; i++) {
      int e = tid + 256 * i;
      int r = e >> 4, kk = e & 15;
      int gr = row0 + r;
      As[r][kk] = (gr < M) ? A[(size_t)gr * K + kc + kk] : 0.f;
    }
#pragma unroll
    for (int i = 0; i < TN / 16; i++) {
      int e = tid + 256 * i;
      int kk = e / TN, n = e % TN;
      Bs[kk][n] = W[(size_t)(kc + kk) * TN + n];
    }
    __syncthreads();
#pragma unroll
    for (int kk = 0; kk < 16; kk++) {
      float a[4];
#pragma unroll
      for (int i = 0; i < 4; i++) a[i] = As[ty * 4 + i][kk];
#pragma unroll
      for (int c = 0; c < NC; c++) {
        const float4 b4 = *(const float4*)&Bs[kk][c * 64 + tx * 4];
#pragma unroll
        for (int i = 0; i < 4; i++) {
          acc[c][i][0] += a[i] * b4.x;
          acc[c][i][1] += a[i] * b4.y;
          acc[c][i][2] += a[i] * b4.z;
          acc[c][i][3] += a[i] * b4.w;
        }
      }
    }
    __syncthreads();
  }

#pragma unroll
  for (int c = 0; c < NC; c++)
#pragma unroll
    for (int i = 0; i < 4; i++) {
      int gr = row0 + ty * 4 + i;
      if (gr < M) {
#pragma unroll
        for (int j = 0; j < 4; j++) {
          int col = c * 64 + tx * 4 + j;
          float v = acc[c][i][j] + bias[col];
          if (ACT) v = silu_f(v);
          C[(size_t)gr * TN + col] = v;
        }
      }
    }
}

// ---------------- fused triplet kernel ----------------
// pbuf/ws layouts: bf16, transposed-for-B, XOR chunk swizzle:
//   elem(row,k) at row*128 + (((k>>3) ^ (row&7)) << 3) + (k&7)

struct G12 {
  float4 a0, a1, a2, a3;  // h[row_ki] segment
  float4 b0, b1, b2, b3;  // h[row_ji] segment
  float4 m0, m1, m2, m3;  // M row segment
};

__device__ __forceinline__ void issue12(G12& g, const float* __restrict__ fa,
                                        const float* __restrict__ fb,
                                        const float* __restrict__ mm, int cseg)
{
  g.a0 = *(const float4*)(fa + cseg + 0);
  g.a1 = *(const float4*)(fa + cseg + 4);
  g.a2 = *(const float4*)(fa + cseg + 8);
  g.a3 = *(const float4*)(fa + cseg + 12);
  g.b0 = *(const float4*)(fb + cseg + 0);
  g.b1 = *(const float4*)(fb + cseg + 4);
  g.b2 = *(const float4*)(fb + cseg + 8);
  g.b3 = *(const float4*)(fb + cseg + 12);
  g.m0 = *(const float4*)(mm + cseg + 0);
  g.m1 = *(const float4*)(mm + cseg + 4);
  g.m2 = *(const float4*)(mm + cseg + 8);
  g.m3 = *(const float4*)(mm + cseg + 12);
}

__device__ __forceinline__ void pack8(const float4& a0, const float4& a1,
                                      const float4& b0, const float4& b1,
                                      const float4& m0, const float4& m1, short8& o)
{
  o[0] = (short)f2bf(a0.x * m0.x * b0.x);
  o[1] = (short)f2bf(a0.y * m0.y * b0.y);
  o[2] = (short)f2bf(a0.z * m0.z * b0.z);
  o[3] = (short)f2bf(a0.w * m0.w * b0.w);
  o[4] = (short)f2bf(a1.x * m1.x * b1.x);
  o[5] = (short)f2bf(a1.y * m1.y * b1.y);
  o[6] = (short)f2bf(a1.z * m1.z * b1.z);
  o[7] = (short)f2bf(a1.w * m1.w * b1.w);
}

__device__ __forceinline__ void pack16(const G12& g, short8& lo, short8& hi)
{
  pack8(g.a0, g.a1, g.b0, g.b1, g.m0, g.m1, lo);
  pack8(g.a2, g.a3, g.b2, g.b3, g.m2, g.m3, hi);
}

__device__ __forceinline__ void writep(unsigned short* pb, int r, int cseg,
                                       const short8& lo, const short8& hi)
{
  const int c0 = cseg >> 3;
  *(short8*)(pb + r * 128 + (((c0) ^ (r & 7)) << 3)) = lo;
  *(short8*)(pb + r * 128 + (((c0 + 1) ^ (r & 7)) << 3)) = hi;
}

__device__ __forceinline__ void mfma_block4(const unsigned short* abuf,
                                            const unsigned short* wsT,
                                            f32x4 (&acc)[4],
                                            int g, int hh, int l15, int l4)
{
  const int arow = 16 * g + l15;
  __builtin_amdgcn_s_setprio(1);
#pragma unroll
  for (int ks = 0; ks < 4; ks++) {
    short8 a = *(const short8*)(abuf + arow * 128 + (((4 * ks + l4) ^ (arow & 7)) << 3));
#pragma unroll
    for (int ct = 0; ct < 4; ct++) {
      const int col = 64 * hh + 16 * ct + l15;
      short8 b = *(const short8*)(wsT + col * 128 + (((4 * ks + l4) ^ (col & 7)) << 3));
      acc[ct] = __builtin_amdgcn_mfma_f32_16x16x32_bf16(a, b, acc[ct], 0, 0, 0);
    }
  }
  __builtin_amdgcn_s_setprio(0);
}

__device__ __forceinline__ void store_s(unsigned short* pbuf, const f32x4 (&acc)[4],
                                        const float* __restrict__ bias,
                                        int g, int hh, int l15, int l4)
{
#pragma unroll
  for (int ct = 0; ct < 4; ct++) {
    const int col = 64 * hh + 16 * ct + l15;
    const float bv = bias[col];
#pragma unroll
    for (int i = 0; i < 4; i++) {
      const int r = 16 * g + 4 * l4 + i;
      float v = silu_f(acc[ct][i] + bv);
      pbuf[r * 128 + ((((col >> 3) ^ (r & 7)) << 3)) + (col & 7)] = f2bf(v);
    }
  }
}

// Assumes T % 64 == 0 (T = 1e6 -> 15625 tiles exactly).
__global__ __launch_bounds__(512, 2)
void triplet_fused(const float* __restrict__ h,
                   const float* __restrict__ M01, const float* __restrict__ M02,
                   const float* __restrict__ Ws01, const float* __restrict__ bs01,
                   const float* __restrict__ Ws02, const float* __restrict__ bs02,
                   const float* __restrict__ Ws,   const float* __restrict__ bs,
                   const int* __restrict__ idx_ji, const int* __restrict__ idx_ki,
                   float* __restrict__ out_acc, int T)
{
  __shared__ unsigned short wsT01[128 * 128];  // 32 KB
  __shared__ unsigned short wsT02[128 * 128];  // 32 KB
  __shared__ unsigned short wsTA[128 * 128];   // 32 KB  (Ws rows 0..127)
  __shared__ unsigned short wsTB[128 * 128];   // 32 KB  (Ws rows 128..255)
  __shared__ unsigned short pbA[64 * 128];     // 16 KB  p-tiles (p01/p02)
  __shared__ unsigned short pbB[64 * 128];     // 16 KB  s-tiles (s01/s02)

  const int tid = threadIdx.x;

  // stage weights: W[k][n] f32 -> wsT[n][k] bf16, swizzled
  for (int e = tid; e < 128 * 128; e += 512) {
    const int k = e >> 7, n = e & 127;
    const int d = n * 128 + ((((k >> 3) ^ (n & 7)) << 3)) + (k & 7);
    wsT01[d] = f2bf(Ws01[e]);
    wsT02[d] = f2bf(Ws02[e]);
    wsTA[d]  = f2bf(Ws[e]);
    wsTB[d]  = f2bf(Ws[128 * 128 + e]);
  }
  __syncthreads();

  const int lane = tid & 63;
  const int wv = tid >> 6;
  const int g = wv & 3;        // row group (16 rows)
  const int hh = wv >> 2;      // col half (64 cols)
  const int l15 = lane & 15, l4 = lane >> 4;
  const f32x4 zero4 = {0.f, 0.f, 0.f, 0.f};

  const int r = tid >> 3;           // gather row 0..63
  const int cseg = (tid & 7) * 16;  // 16 cols per thread
  const int ntiles = T >> 6;

  int tile = blockIdx.x;
  if (tile >= ntiles) return;

  // prologue: first tile's p01 inputs -> regs -> packed
  int trow = tile * 64 + r;
  int ek = idx_ki[trow], ej = idx_ji[trow];
  short8 p01lo, p01hi;
  {
    G12 g1;
    issue12(g1, h + (size_t)ek * 256, h + (size_t)ej * 256, M01 + (size_t)trow * 128, cseg);
    pack16(g1, p01lo, p01hi);
  }

  for (; tile < ntiles; tile += gridDim.x) {
    trow = tile * 64 + r;
    const int rbase = tile << 6;
    f32x4 acc3[4] = {zero4, zero4, zero4, zero4};

    // ---- P1: write p01 -> pbA ; issue p02 loads (same rows, second half) ----
    writep(pbA, r, cseg, p01lo, p01hi);
    G12 g2;
    issue12(g2, h + (size_t)ek * 256 + 128, h + (size_t)ej * 256 + 128,
            M02 + (size_t)trow * 128, cseg);
    TSYNC();

    // ---- P2: MFMA1 (pbA,Ws01)->acc1 ; store s01->pbB ; load next-tile idx ----
    int trow_n = (tile + gridDim.x) * 64 + r;
    if (trow_n >= T) trow_n = T - 1;       // clamp: last pipeline stage unused
    const int ekn = idx_ki[trow_n], ejn = idx_ji[trow_n];
    {
      f32x4 acc1[4] = {zero4, zero4, zero4, zero4};
      mfma_block4(pbA, wsT01, acc1, g, hh, l15, l4);
      store_s(pbB, acc1, bs01, g, hh, l15, l4);
    }
    TSYNC();

    // ---- P3: MFMA2 (pbB,WsA)->acc3 ; pack p02 ; write p02 -> pbA ----
    mfma_block4(pbB, wsTA, acc3, g, hh, l15, l4);
    {
      short8 p02lo, p02hi;
      pack16(g2, p02lo, p02hi);
      writep(pbA, r, cseg, p02lo, p02hi);
    }
    TSYNC();

    // ---- P4: issue next-tile p01 loads + jrow loads ; MFMA3 (pbA,Ws02)->acc2 ; store s02->pbB ----
    G12 g1n;
    issue12(g1n, h + (size_t)ekn * 256, h + (size_t)ejn * 256,
            M01 + (size_t)trow_n * 128, cseg);
    int jrow[4];
#pragma unroll
    for (int i = 0; i < 4; i++)
      jrow[i] = idx_ji[rbase + 16 * g + 4 * l4 + i];
    {
      f32x4 acc2[4] = {zero4, zero4, zero4, zero4};
      mfma_block4(pbA, wsT02, acc2, g, hh, l15, l4);
      store_s(pbB, acc2, bs02, g, hh, l15, l4);
    }
    TSYNC();

    // ---- P5: MFMA4 (pbB,WsB)->acc3 ; epilogue atomics (never drained) ; pack next p01 ----
    mfma_block4(pbB, wsTB, acc3, g, hh, l15, l4);
#pragma unroll
    for (int ct = 0; ct < 4; ct++) {
      const int col = 64 * hh + 16 * ct + l15;
      const float bv = bs[col];
#pragma unroll
      for (int i = 0; i < 4; i++)
        atomicAdd(out_acc + (size_t)jrow[i] * 128 + col, silu_f(acc3[ct][i] + bv));
    }
    pack16(g1n, p01lo, p01hi);
    ek = ekn; ej = ejn;
    TSYNC();
  }
}

extern "C" void kernel_launch(void* const* d_in, const int* in_sizes, int n_in,
                              void* d_out, int out_size, void* d_ws, size_t ws_size,
                              hipStream_t stream)
{
  const float* f    = (const float*)d_in[0];
  const float* M01  = (const float*)d_in[1];
  const float* M02  = (const float*)d_in[2];
  const float* W1   = (const float*)d_in[3];
  const float* b1   = (const float*)d_in[4];
  const float* W2   = (const float*)d_in[5];
  const float* b2   = (const float*)d_in[6];
  const float* Ws01 = (const float*)d_in[7];
  const float* bs01 = (const float*)d_in[8];
  const float* Ws02 = (const float*)d_in[9];
  const float* bs02 = (const float*)d_in[10];
  const float* Ws   = (const float*)d_in[11];
  const float* bs   = (const float*)d_in[12];
  const float* Wout = (const float*)d_in[13];
  const float* bout = (const float*)d_in[14];
  const int* idx_ji = (const int*)d_in[16];
  const int* idx_ki = (const int*)d_in[17];

  const int E = in_sizes[0] / 256;
  const int T = in_sizes[1] / 128;

  float* h = (float*)d_ws;          // [E][256] f32 (102.4 MB)
  float* out_acc = (float*)d_out;   // [E][128] f32 accumulator, then final out in-place

  const int mb = (E + 63) / 64;
  // edge MLP: h1 = silu(f@W1+b1); h = silu(h1@W2+b2) (in-place, row-block exclusive)
  gemm_rowtile<256, 1><<<mb, 256, 0, stream>>>(f, W1, b1, h, E, 256);
  gemm_rowtile<256, 1><<<mb, 256, 0, stream>>>(h, W2, b2, h, E, 256);

  hipMemsetAsync(d_out, 0, (size_t)E * 128 * sizeof(float), stream);

  const int ntiles = (T + 63) / 64;
  const int grid = ntiles < 256 ? ntiles : 256;  // 1 block/CU, persistent
  triplet_fused<<<grid, 512, 0, stream>>>(h, M01, M02, Ws01, bs01, Ws02, bs02,
                                          Ws, bs, idx_ji, idx_ki, out_acc, T);

  // out = out_acc @ Wout + bout (in-place on d_out, row-block exclusive)
  gemm_rowtile<128, 0><<<mb, 256, 0, stream>>>(out_acc, Wout, bout, out_acc, E, 128);
}

// Round 4
// 1254.681 us; speedup vs baseline: 1.0999x; 1.0999x over previous
//
#include <hip/hip_runtime.h>

typedef __attribute__((ext_vector_type(8))) short short8;
typedef __attribute__((ext_vector_type(4))) float f32x4;

__device__ __forceinline__ float silu_f(float x) { return x / (1.0f + __expf(-x)); }

__device__ __forceinline__ unsigned short f2bf(float x) {
  unsigned u = __float_as_uint(x);
  u += 0x7FFFu + ((u >> 16) & 1u);
  return (unsigned short)(u >> 16);
}
__device__ __forceinline__ float bf2f(unsigned short v) {
  return __uint_as_float(((unsigned)v) << 16);
}

// raw barrier: LDS writes visible, sync, do NOT drain vmcnt
#define TSYNC() do { asm volatile("s_waitcnt lgkmcnt(0)" ::: "memory"); \
                     __builtin_amdgcn_s_barrier(); \
                     asm volatile("" ::: "memory"); } while (0)

// ---------------- generic f32-accum row-tile GEMM: C = act(A @ W + b) ----------------
// One block owns 64 rows x ALL TN cols -> in-place (C==A) safe per row-block.
// INBF/OUTBF: bf16 (ushort) vs f32 storage for A / C.
template<int TN, int ACT, int INBF, int OUTBF>
__global__ __launch_bounds__(256)
void gemm_rowtile(const void* A_, const float* __restrict__ W,
                  const float* __restrict__ bias, void* C_, int M, int K)
{
  constexpr int NC = TN / 64;
  __shared__ float As[64][17];
  __shared__ float Bs[16][TN + 4];
  const int tid = threadIdx.x;
  const int tx = tid & 15, ty = tid >> 4;
  const int row0 = blockIdx.x * 64;

  float acc[NC][4][4];
#pragma unroll
  for (int c = 0; c < NC; c++)
#pragma unroll
    for (int i = 0; i < 4; i++)
#pragma unroll
      for (int j = 0; j < 4; j++) acc[c][i][j] = 0.f;

  for (int kc = 0; kc < K; kc += 16) {
#pragma unroll
    for (int i = 0; i < 4; i++) {
      int e = tid + 256 * i;
      int r = e >> 4, kk = e & 15;
      int gr = row0 + r;
      float v = 0.f;
      if (gr < M) {
        size_t idx = (size_t)gr * K + kc + kk;
        v = INBF ? bf2f(((const unsigned short*)A_)[idx]) : ((const float*)A_)[idx];
      }
      As[r][kk] = v;
    }
#pragma unroll
    for (int i = 0; i < TN / 16; i++) {
      int e = tid + 256 * i;
      int kk = e / TN, n = e % TN;
      Bs[kk][n] = W[(size_t)(kc + kk) * TN + n];
    }
    __syncthreads();
#pragma unroll
    for (int kk = 0; kk < 16; kk++) {
      float a[4];
#pragma unroll
      for (int i = 0; i < 4; i++) a[i] = As[ty * 4 + i][kk];
#pragma unroll
      for (int c = 0; c < NC; c++) {
        const float4 b4 = *(const float4*)&Bs[kk][c * 64 + tx * 4];
#pragma unroll
        for (int i = 0; i < 4; i++) {
          acc[c][i][0] += a[i] * b4.x;
          acc[c][i][1] += a[i] * b4.y;
          acc[c][i][2] += a[i] * b4.z;
          acc[c][i][3] += a[i] * b4.w;
        }
      }
    }
    __syncthreads();
  }

#pragma unroll
  for (int c = 0; c < NC; c++)
#pragma unroll
    for (int i = 0; i < 4; i++) {
      int gr = row0 + ty * 4 + i;
      if (gr < M) {
#pragma unroll
        for (int j = 0; j < 4; j++) {
          int col = c * 64 + tx * 4 + j;
          float v = acc[c][i][j] + bias[col];
          if (ACT) v = silu_f(v);
          size_t idx = (size_t)gr * TN + col;
          if (OUTBF) ((unsigned short*)C_)[idx] = f2bf(v);
          else       ((float*)C_)[idx] = v;
        }
      }
    }
}

// ---------------- counting sort of idx_ji (per-call, idempotent) ----------------
__global__ void hist_k(const int* __restrict__ ji, int* __restrict__ cnt, int T) {
  int t = blockIdx.x * 256 + threadIdx.x;
  const int stride = gridDim.x * 256;
  for (; t < T; t += stride) atomicAdd(&cnt[ji[t]], 1);
}

__global__ void scan1_k(const int* __restrict__ cnt, int* __restrict__ csum, int E) {
  __shared__ int red[256];
  const int c0 = blockIdx.x * 2048;
  int s = 0;
  for (int i = threadIdx.x; i < 2048; i += 256) {
    int e = c0 + i;
    if (e < E) s += cnt[e];
  }
  red[threadIdx.x] = s;
  __syncthreads();
  for (int o = 128; o > 0; o >>= 1) {
    if (threadIdx.x < o) red[threadIdx.x] += red[threadIdx.x + o];
    __syncthreads();
  }
  if (threadIdx.x == 0) csum[blockIdx.x] = red[0];
}

__global__ void scan2_k(int* __restrict__ csum, int n) {
  if (threadIdx.x == 0 && blockIdx.x == 0) {
    int acc = 0;
    for (int i = 0; i < n; i++) { int v = csum[i]; csum[i] = acc; acc += v; }
  }
}

__global__ void scan3_k(const int* __restrict__ cnt, const int* __restrict__ csum,
                        int* __restrict__ off, int E) {
  __shared__ int ts[256];
  const int c0 = blockIdx.x * 2048;
  const int tid = threadIdx.x;
  int loc[8];
  int s = 0;
#pragma unroll
  for (int k = 0; k < 8; k++) {
    int e = c0 + tid * 8 + k;
    loc[k] = (e < E) ? cnt[e] : 0;
    s += loc[k];
  }
  ts[tid] = s;
  __syncthreads();
  for (int o = 1; o < 256; o <<= 1) {
    int v = (tid >= o) ? ts[tid - o] : 0;
    __syncthreads();
    ts[tid] += v;
    __syncthreads();
  }
  int base = csum[blockIdx.x] + ((tid > 0) ? ts[tid - 1] : 0);
#pragma unroll
  for (int k = 0; k < 8; k++) {
    int e = c0 + tid * 8 + k;
    if (e < E) { off[e] = base; base += loc[k]; }
  }
}

__global__ void scatter_k(const int* __restrict__ ji, int* __restrict__ cursor,
                          int* __restrict__ perm, int T) {
  int t = blockIdx.x * 256 + threadIdx.x;
  const int stride = gridDim.x * 256;
  for (; t < T; t += stride) {
    int e = ji[t];
    int p = atomicAdd(&cursor[e], 1);
    perm[p] = t;
  }
}

// ---------------- fused triplet kernel (sorted order) ----------------
// p/s tiles: bf16, transposed-for-B, XOR chunk swizzle:
//   elem(row,k) at row*128 + (((k>>3) ^ (row&7)) << 3) + (k&7)

struct G12 {
  short8 a0, a1;   // h[ki] 16 bf16
  short8 b0, b1;   // h[ji] 16 bf16
  float4 m0, m1, m2, m3;  // M row 16 f32
};

__device__ __forceinline__ void issue12(G12& g, const unsigned short* __restrict__ fa,
                                        const unsigned short* __restrict__ fb,
                                        const float* __restrict__ mm, int cseg)
{
  g.a0 = *(const short8*)(fa + cseg);
  g.a1 = *(const short8*)(fa + cseg + 8);
  g.b0 = *(const short8*)(fb + cseg);
  g.b1 = *(const short8*)(fb + cseg + 8);
  g.m0 = *(const float4*)(mm + cseg + 0);
  g.m1 = *(const float4*)(mm + cseg + 4);
  g.m2 = *(const float4*)(mm + cseg + 8);
  g.m3 = *(const float4*)(mm + cseg + 12);
}

__device__ __forceinline__ void pack8x(const short8& a, const short8& b,
                                       const float4& m0, const float4& m1, short8& o)
{
  o[0] = (short)f2bf(bf2f((unsigned short)a[0]) * m0.x * bf2f((unsigned short)b[0]));
  o[1] = (short)f2bf(bf2f((unsigned short)a[1]) * m0.y * bf2f((unsigned short)b[1]));
  o[2] = (short)f2bf(bf2f((unsigned short)a[2]) * m0.z * bf2f((unsigned short)b[2]));
  o[3] = (short)f2bf(bf2f((unsigned short)a[3]) * m0.w * bf2f((unsigned short)b[3]));
  o[4] = (short)f2bf(bf2f((unsigned short)a[4]) * m1.x * bf2f((unsigned short)b[4]));
  o[5] = (short)f2bf(bf2f((unsigned short)a[5]) * m1.y * bf2f((unsigned short)b[5]));
  o[6] = (short)f2bf(bf2f((unsigned short)a[6]) * m1.z * bf2f((unsigned short)b[6]));
  o[7] = (short)f2bf(bf2f((unsigned short)a[7]) * m1.w * bf2f((unsigned short)b[7]));
}

__device__ __forceinline__ void pack16(const G12& g, short8& lo, short8& hi)
{
  pack8x(g.a0, g.b0, g.m0, g.m1, lo);
  pack8x(g.a1, g.b1, g.m2, g.m3, hi);
}

__device__ __forceinline__ void writep(unsigned short* pb, int r, int cseg,
                                       const short8& lo, const short8& hi)
{
  const int c0 = cseg >> 3;
  *(short8*)(pb + r * 128 + (((c0) ^ (r & 7)) << 3)) = lo;
  *(short8*)(pb + r * 128 + (((c0 + 1) ^ (r & 7)) << 3)) = hi;
}

__device__ __forceinline__ void mfma_block4(const unsigned short* abuf,
                                            const unsigned short* wsT,
                                            f32x4 (&acc)[4],
                                            int g, int hh, int l15, int l4)
{
  const int arow = 16 * g + l15;
  __builtin_amdgcn_s_setprio(1);
#pragma unroll
  for (int ks = 0; ks < 4; ks++) {
    short8 a = *(const short8*)(abuf + arow * 128 + (((4 * ks + l4) ^ (arow & 7)) << 3));
#pragma unroll
    for (int ct = 0; ct < 4; ct++) {
      const int col = 64 * hh + 16 * ct + l15;
      short8 b = *(const short8*)(wsT + col * 128 + (((4 * ks + l4) ^ (col & 7)) << 3));
      acc[ct] = __builtin_amdgcn_mfma_f32_16x16x32_bf16(a, b, acc[ct], 0, 0, 0);
    }
  }
  __builtin_amdgcn_s_setprio(0);
}

__device__ __forceinline__ void store_s(unsigned short* pbuf, const f32x4 (&acc)[4],
                                        const float* __restrict__ bias,
                                        int g, int hh, int l15, int l4)
{
#pragma unroll
  for (int ct = 0; ct < 4; ct++) {
    const int col = 64 * hh + 16 * ct + l15;
    const float bv = bias[col];
#pragma unroll
    for (int i = 0; i < 4; i++) {
      const int r = 16 * g + 4 * l4 + i;
      float v = silu_f(acc[ct][i] + bv);
      pbuf[r * 128 + ((((col >> 3) ^ (r & 7)) << 3)) + (col & 7)] = f2bf(v);
    }
  }
}

// Assumes T % 64 == 0 (T = 1e6 -> 15625 tiles exactly).
__global__ __launch_bounds__(512, 2)
void triplet_fused(const unsigned short* __restrict__ h,
                   const float* __restrict__ M01, const float* __restrict__ M02,
                   const float* __restrict__ Ws01, const float* __restrict__ bs01,
                   const float* __restrict__ Ws02, const float* __restrict__ bs02,
                   const float* __restrict__ Ws,   const float* __restrict__ bs,
                   const int* __restrict__ idx_ji, const int* __restrict__ idx_ki,
                   const int* __restrict__ perm,
                   float* __restrict__ out_acc, int T)
{
  __shared__ unsigned short wsT01[128 * 128];  // 32 KB
  __shared__ unsigned short wsT02[128 * 128];  // 32 KB
  __shared__ unsigned short wsTA[128 * 128];   // 32 KB (Ws rows 0..127)
  __shared__ unsigned short wsTB[128 * 128];   // 32 KB (Ws rows 128..255)
  __shared__ unsigned short pbA[64 * 128];     // 16 KB: p01/p02, then poolA f32[64][64]
  __shared__ unsigned short pbB[64 * 128];     // 16 KB: s01/s02, then poolB f32[64][64]
  float* const poolA = (float*)pbA;
  float* const poolB = (float*)pbB;

  const int tid = threadIdx.x;

  for (int e = tid; e < 128 * 128; e += 512) {
    const int k = e >> 7, n = e & 127;
    const int d = n * 128 + ((((k >> 3) ^ (n & 7)) << 3)) + (k & 7);
    wsT01[d] = f2bf(Ws01[e]);
    wsT02[d] = f2bf(Ws02[e]);
    wsTA[d]  = f2bf(Ws[e]);
    wsTB[d]  = f2bf(Ws[128 * 128 + e]);
  }
  __syncthreads();

  const int lane = tid & 63;
  const int wv = tid >> 6;
  const int g = wv & 3;        // row group (16 rows)
  const int hh = wv >> 2;      // col half (64 cols)
  const int l15 = lane & 15, l4 = lane >> 4;
  const f32x4 zero4 = {0.f, 0.f, 0.f, 0.f};

  const int r = tid >> 3;           // gather row 0..63
  const int cseg = (tid & 7) * 16;  // 16 cols per thread
  const int ntiles = T >> 6;

  int tile = blockIdx.x;
  if (tile >= ntiles) return;

  // prologue: first tile's p01 inputs
  int trow = perm[tile * 64 + r];
  int ek = idx_ki[trow], ej = idx_ji[trow];
  short8 p01lo, p01hi;
  {
    G12 g1;
    issue12(g1, h + (size_t)ek * 256, h + (size_t)ej * 256,
            M01 + (size_t)trow * 128, cseg);
    pack16(g1, p01lo, p01hi);
  }

  for (; tile < ntiles; tile += gridDim.x) {
    const int rbase = tile << 6;
    f32x4 acc3[4] = {zero4, zero4, zero4, zero4};

    // ---- P1: write p01 -> pbA ; issue p02 loads ; issue per-lane jr loads ----
    writep(pbA, r, cseg, p01lo, p01hi);
    G12 g2;
    issue12(g2, h + (size_t)ek * 256 + 128, h + (size_t)ej * 256 + 128,
            M02 + (size_t)trow * 128, cseg);
    const int pj = perm[rbase + lane];   // sorted row `lane` of this tile
    TSYNC();

    // ---- P2: MFMA1 -> s01 -> pbB ; next-tile idx prefetch ; jrv load ----
    int srow_n = (tile + gridDim.x) * 64 + r;
    if (srow_n >= T) srow_n = T - 1;
    const int trow_n = perm[srow_n];
    const int ekn = idx_ki[trow_n], ejn = idx_ji[trow_n];
    const int jrv = idx_ji[pj];          // this tile's edge id for row `lane`
    {
      f32x4 acc1[4] = {zero4, zero4, zero4, zero4};
      mfma_block4(pbA, wsT01, acc1, g, hh, l15, l4);
      store_s(pbB, acc1, bs01, g, hh, l15, l4);
    }
    TSYNC();

    // ---- P3: MFMA2 (s01,WsA)->acc3 ; pack p02 -> pbA ----
    mfma_block4(pbB, wsTA, acc3, g, hh, l15, l4);
    {
      short8 lo, hi;
      pack16(g2, lo, hi);
      writep(pbA, r, cseg, lo, hi);
    }
    TSYNC();

    // ---- P4: issue next p01 ; MFMA3 -> s02 -> pbB ----
    G12 g1n;
    issue12(g1n, h + (size_t)ekn * 256, h + (size_t)ejn * 256,
            M01 + (size_t)trow_n * 128, cseg);
    {
      f32x4 acc2[4] = {zero4, zero4, zero4, zero4};
      mfma_block4(pbA, wsT02, acc2, g, hh, l15, l4);
      store_s(pbB, acc2, bs02, g, hh, l15, l4);
    }
    TSYNC();

    // ---- P5: MFMA4 (s02,WsB)->acc3 ; pack next p01 ----
    mfma_block4(pbB, wsTB, acc3, g, hh, l15, l4);
    pack16(g1n, p01lo, p01hi);
    TSYNC();

    // ---- P6: sfin = silu(acc3+bs) f32 -> poolA/poolB ----
    {
      float* const pool = hh ? poolB : poolA;
#pragma unroll
      for (int ct = 0; ct < 4; ct++) {
        const float bv = bs[64 * hh + 16 * ct + l15];
#pragma unroll
        for (int i = 0; i < 4; i++)
          pool[(16 * g + 4 * l4 + i) * 64 + 16 * ct + l15] = silu_f(acc3[ct][i] + bv);
      }
    }
    TSYNC();

    // ---- P7: segment-sum over sorted rows; store interior, atomic boundary ----
    {
      const int jprev = __shfl_up(jrv, 1, 64);
      const bool isst = (lane == 0) || (jrv != jprev);
      unsigned long long mask = __ballot(isst);
      const int nseg = __popcll(mask);
      for (int s = wv; s < nseg; s += 8) {
        unsigned long long m2 = mask;
        for (int d = 0; d < s; d++) m2 &= m2 - 1;   // drop s lowest set bits
        const int fr = __ffsll(m2) - 1;
        unsigned long long m3 = m2 & (m2 - 1);
        const int lr = m3 ? (__ffsll(m3) - 2) : 63;
        const int e = __shfl(jrv, fr, 64);
        float s0 = 0.f, s1 = 0.f;
        for (int rr = fr; rr <= lr; ++rr) {
          s0 += poolA[rr * 64 + lane];
          s1 += poolB[rr * 64 + lane];
        }
        float* dst = out_acc + (size_t)e * 128;
        if (fr == 0 || lr == 63) {
          atomicAdd(dst + lane, s0);
          atomicAdd(dst + 64 + lane, s1);
        } else {
          dst[lane] = s0;
          dst[64 + lane] = s1;
        }
      }
    }
    trow = trow_n; ek = ekn; ej = ejn;
    TSYNC();  // pool reads done before next tile's P1 overwrites pbA
  }
}

extern "C" void kernel_launch(void* const* d_in, const int* in_sizes, int n_in,
                              void* d_out, int out_size, void* d_ws, size_t ws_size,
                              hipStream_t stream)
{
  const float* f    = (const float*)d_in[0];
  const float* M01  = (const float*)d_in[1];
  const float* M02  = (const float*)d_in[2];
  const float* W1   = (const float*)d_in[3];
  const float* b1   = (const float*)d_in[4];
  const float* W2   = (const float*)d_in[5];
  const float* b2   = (const float*)d_in[6];
  const float* Ws01 = (const float*)d_in[7];
  const float* bs01 = (const float*)d_in[8];
  const float* Ws02 = (const float*)d_in[9];
  const float* bs02 = (const float*)d_in[10];
  const float* Ws   = (const float*)d_in[11];
  const float* bs   = (const float*)d_in[12];
  const float* Wout = (const float*)d_in[13];
  const float* bout = (const float*)d_in[14];
  const int* idx_ji = (const int*)d_in[16];
  const int* idx_ki = (const int*)d_in[17];

  const int E = in_sizes[0] / 256;
  const int T = in_sizes[1] / 128;

  // ws layout (bf16 h frees room; total ~56 MB < proven >=102.4 MB)
  char* w = (char*)d_ws;
  unsigned short* hbuf = (unsigned short*)w;                    // [E][256] bf16
  size_t o = ((size_t)E * 256 * 2 + 255) & ~(size_t)255;
  int* cnt = (int*)(w + o);  o += ((size_t)E * 4 + 255) & ~(size_t)255;
  int* off = (int*)(w + o);  o += ((size_t)E * 4 + 255) & ~(size_t)255;
  int* csum = (int*)(w + o); o += 4096;
  int* perm = (int*)(w + o);                                    // [T]

  float* out_acc = (float*)d_out;

  const int mb = (E + 63) / 64;
  // edge MLP: h1 = silu(f@W1+b1) [bf16]; h = silu(h1@W2+b2) [bf16, in-place]
  gemm_rowtile<256, 1, 0, 1><<<mb, 256, 0, stream>>>(f, W1, b1, hbuf, E, 256);
  gemm_rowtile<256, 1, 1, 1><<<mb, 256, 0, stream>>>(hbuf, W2, b2, hbuf, E, 256);

  // counting sort of idx_ji -> perm (recomputed every call; graph-replay safe)
  hipMemsetAsync(cnt, 0, (size_t)E * 4, stream);
  hist_k<<<1024, 256, 0, stream>>>(idx_ji, cnt, T);
  const int nchunks = (E + 2047) / 2048;
  scan1_k<<<nchunks, 256, 0, stream>>>(cnt, csum, E);
  scan2_k<<<1, 64, 0, stream>>>(csum, nchunks);
  scan3_k<<<nchunks, 256, 0, stream>>>(cnt, csum, off, E);
  scatter_k<<<1024, 256, 0, stream>>>(idx_ji, off, perm, T);

  hipMemsetAsync(d_out, 0, (size_t)E * 128 * sizeof(float), stream);

  const int ntiles = (T + 63) / 64;
  const int grid = ntiles < 256 ? ntiles : 256;  // persistent, 1 block/CU
  triplet_fused<<<grid, 512, 0, stream>>>(hbuf, M01, M02, Ws01, bs01, Ws02, bs02,
                                          Ws, bs, idx_ji, idx_ki, perm, out_acc, T);

  // out = out_acc @ Wout + bout (in-place on d_out)
  gemm_rowtile<128, 0, 0, 0><<<mb, 256, 0, stream>>>(out_acc, Wout, bout, out_acc, E, 128);
}

// Round 5
// 988.636 us; speedup vs baseline: 1.3959x; 1.2691x over previous
//
#include <hip/hip_runtime.h>

typedef __attribute__((ext_vector_type(8))) short short8;
typedef __attribute__((ext_vector_type(4))) float f32x4;

__device__ __forceinline__ float silu_f(float x) { return x / (1.0f + __expf(-x)); }

__device__ __forceinline__ unsigned short f2bf(float x) {
  unsigned u = __float_as_uint(x);
  u += 0x7FFFu + ((u >> 16) & 1u);
  return (unsigned short)(u >> 16);
}
__device__ __forceinline__ float bf2f(unsigned short v) {
  return __uint_as_float(((unsigned)v) << 16);
}
__device__ __forceinline__ unsigned cvtpk_bf16(float lo, float hi) {
  unsigned r;
  asm("v_cvt_pk_bf16_f32 %0, %1, %2" : "=v"(r) : "v"(lo), "v"(hi));
  return r;
}

// raw barrier: LDS writes visible, sync, do NOT drain vmcnt
#define TSYNC() do { asm volatile("s_waitcnt lgkmcnt(0)" ::: "memory"); \
                     __builtin_amdgcn_s_barrier(); \
                     asm volatile("" ::: "memory"); } while (0)

// ---------------- weight prep: W[K][N] f32 -> panel-swizzled bf16 hi/lo ----------------
// panel kp = k>>6; addr = kp*N*64 + n*64 + ((((k&63)>>3) ^ (n&7))<<3) + (k&7)
__global__ void prep_w(const float* __restrict__ W, unsigned short* __restrict__ wh,
                       unsigned short* __restrict__ wl, int K, int N)
{
  int e = blockIdx.x * 256 + threadIdx.x;
  if (e >= K * N) return;
  int k = e / N, n = e % N;
  float w = W[e];
  unsigned short hi = f2bf(w);
  unsigned short lo = f2bf(w - bf2f(hi));
  int kp = k >> 6, kk = k & 63;
  size_t dst = (size_t)kp * N * 64 + (size_t)n * 64 + ((((kk >> 3) ^ (n & 7)) << 3)) + (kk & 7);
  wh[dst] = hi;
  wl[dst] = lo;
}

// ---------------- MLP GEMM: C = silu(A @ W + b), K=256, N=256, bf16 out ----------------
// split-precision: W = Whi + Wlo (always), A split when ASPLIT (f32 input).
template<int INBF, int ASPLIT>
__global__ __launch_bounds__(512)
void mlp_gemm(const void* A_, const unsigned short* __restrict__ wh,
              const unsigned short* __restrict__ wl,
              const float* __restrict__ bias, unsigned short* __restrict__ C, int M)
{
  __shared__ unsigned short aTh[64 * 64], aTl[64 * 64];   // 16 KB
  __shared__ unsigned short whb[256 * 64], wlb[256 * 64]; // 64 KB -> 80 KB total
  const int tid = threadIdx.x;
  const int lane = tid & 63, wv = tid >> 6;
  const int g = wv & 3, hh = wv >> 2;   // rows 16g.., cols 128hh..
  const int l15 = lane & 15, l4 = lane >> 4;
  const int row0 = blockIdx.x * 64;
  const int r = tid >> 3, kseg = (tid & 7) * 8;
  const f32x4 zero4 = {0.f, 0.f, 0.f, 0.f};

  f32x4 acc[8];
#pragma unroll
  for (int nt = 0; nt < 8; nt++) acc[nt] = zero4;

  for (int kp = 0; kp < 4; kp++) {
    // stage A panel [64 rows x 64 k]
    {
      const int grow = row0 + r;
      float x[8];
      if (grow < M) {
        if (INBF) {
          short8 v = *(const short8*)((const unsigned short*)A_ + (size_t)grow * 256 + kp * 64 + kseg);
#pragma unroll
          for (int j = 0; j < 8; j++) x[j] = bf2f((unsigned short)v[j]);
        } else {
          const float* ap = (const float*)A_ + (size_t)grow * 256 + kp * 64 + kseg;
          float4 v0 = *(const float4*)ap;
          float4 v1 = *(const float4*)(ap + 4);
          x[0] = v0.x; x[1] = v0.y; x[2] = v0.z; x[3] = v0.w;
          x[4] = v1.x; x[5] = v1.y; x[6] = v1.z; x[7] = v1.w;
        }
      } else {
#pragma unroll
        for (int j = 0; j < 8; j++) x[j] = 0.f;
      }
      union { short8 s; unsigned short us[8]; } H, L;
#pragma unroll
      for (int j = 0; j < 8; j++) {
        H.us[j] = f2bf(x[j]);
        L.us[j] = ASPLIT ? f2bf(x[j] - bf2f(H.us[j])) : (unsigned short)0;
      }
      const int dst = r * 64 + ((((kseg >> 3) ^ (r & 7)) << 3));
      *(short8*)(aTh + dst) = H.s;
      if (ASPLIT) *(short8*)(aTl + dst) = L.s;
    }
    // copy W panels (32 KB each, linear)
    {
      const short8* srcH = (const short8*)(wh + (size_t)kp * 16384);
      const short8* srcL = (const short8*)(wl + (size_t)kp * 16384);
#pragma unroll
      for (int i = 0; i < 4; i++) {
        ((short8*)whb)[tid + 512 * i] = srcH[tid + 512 * i];
        ((short8*)wlb)[tid + 512 * i] = srcL[tid + 512 * i];
      }
    }
    __syncthreads();
#pragma unroll
    for (int ks = 0; ks < 2; ks++) {
      const int arow = 16 * g + l15;
      const int aof = arow * 64 + (((4 * ks + l4) ^ (arow & 7)) << 3);
      short8 ah = *(const short8*)(aTh + aof);
      short8 al = *(const short8*)(aTl + aof);
#pragma unroll
      for (int nt = 0; nt < 8; nt++) {
        const int col = 128 * hh + 16 * nt + l15;
        const int bof = col * 64 + (((4 * ks + l4) ^ (col & 7)) << 3);
        short8 bh = *(const short8*)(whb + bof);
        short8 bl = *(const short8*)(wlb + bof);
        acc[nt] = __builtin_amdgcn_mfma_f32_16x16x32_bf16(ah, bh, acc[nt], 0, 0, 0);
        acc[nt] = __builtin_amdgcn_mfma_f32_16x16x32_bf16(ah, bl, acc[nt], 0, 0, 0);
        if (ASPLIT)
          acc[nt] = __builtin_amdgcn_mfma_f32_16x16x32_bf16(al, bh, acc[nt], 0, 0, 0);
      }
    }
    __syncthreads();
  }
#pragma unroll
  for (int nt = 0; nt < 8; nt++) {
    const int col = 128 * hh + 16 * nt + l15;
    const float bv = bias[col];
#pragma unroll
    for (int i = 0; i < 4; i++) {
      const int row = row0 + 16 * g + 4 * l4 + i;
      if (row < M) C[(size_t)row * 256 + col] = f2bf(silu_f(acc[nt][i] + bv));
    }
  }
}

// ---------------- final GEMM: C = A @ Wout + b, K=128, N=128, f32 in/out, 3-term split ----------------
__global__ __launch_bounds__(512)
void final_gemm(const float* __restrict__ A, const unsigned short* __restrict__ wh,
                const unsigned short* __restrict__ wl,
                const float* __restrict__ bias, float* __restrict__ C, int M)
{
  __shared__ unsigned short aTh[64 * 64], aTl[64 * 64];   // 16 KB
  __shared__ unsigned short whb[128 * 64], wlb[128 * 64]; // 32 KB -> 48 KB total
  const int tid = threadIdx.x;
  const int lane = tid & 63, wv = tid >> 6;
  const int g = wv & 3, hh = wv >> 2;   // rows 16g.., cols 64hh..
  const int l15 = lane & 15, l4 = lane >> 4;
  const int row0 = blockIdx.x * 64;
  const int r = tid >> 3, kseg = (tid & 7) * 8;
  const f32x4 zero4 = {0.f, 0.f, 0.f, 0.f};

  f32x4 acc[4];
#pragma unroll
  for (int nt = 0; nt < 4; nt++) acc[nt] = zero4;

  for (int kp = 0; kp < 2; kp++) {
    {
      const int grow = row0 + r;
      float x[8];
      if (grow < M) {
        const float* ap = A + (size_t)grow * 128 + kp * 64 + kseg;
        float4 v0 = *(const float4*)ap;
        float4 v1 = *(const float4*)(ap + 4);
        x[0] = v0.x; x[1] = v0.y; x[2] = v0.z; x[3] = v0.w;
        x[4] = v1.x; x[5] = v1.y; x[6] = v1.z; x[7] = v1.w;
      } else {
#pragma unroll
        for (int j = 0; j < 8; j++) x[j] = 0.f;
      }
      union { short8 s; unsigned short us[8]; } H, L;
#pragma unroll
      for (int j = 0; j < 8; j++) {
        H.us[j] = f2bf(x[j]);
        L.us[j] = f2bf(x[j] - bf2f(H.us[j]));
      }
      const int dst = r * 64 + ((((kseg >> 3) ^ (r & 7)) << 3));
      *(short8*)(aTh + dst) = H.s;
      *(short8*)(aTl + dst) = L.s;
    }
    {
      const short8* srcH = (const short8*)(wh + (size_t)kp * 8192);
      const short8* srcL = (const short8*)(wl + (size_t)kp * 8192);
#pragma unroll
      for (int i = 0; i < 2; i++) {
        ((short8*)whb)[tid + 512 * i] = srcH[tid + 512 * i];
        ((short8*)wlb)[tid + 512 * i] = srcL[tid + 512 * i];
      }
    }
    __syncthreads();
#pragma unroll
    for (int ks = 0; ks < 2; ks++) {
      const int arow = 16 * g + l15;
      const int aof = arow * 64 + (((4 * ks + l4) ^ (arow & 7)) << 3);
      short8 ah = *(const short8*)(aTh + aof);
      short8 al = *(const short8*)(aTl + aof);
#pragma unroll
      for (int nt = 0; nt < 4; nt++) {
        const int col = 64 * hh + 16 * nt + l15;
        const int bof = col * 64 + (((4 * ks + l4) ^ (col & 7)) << 3);
        short8 bh = *(const short8*)(whb + bof);
        short8 bl = *(const short8*)(wlb + bof);
        acc[nt] = __builtin_amdgcn_mfma_f32_16x16x32_bf16(ah, bh, acc[nt], 0, 0, 0);
        acc[nt] = __builtin_amdgcn_mfma_f32_16x16x32_bf16(ah, bl, acc[nt], 0, 0, 0);
        acc[nt] = __builtin_amdgcn_mfma_f32_16x16x32_bf16(al, bh, acc[nt], 0, 0, 0);
      }
    }
    __syncthreads();
  }
#pragma unroll
  for (int nt = 0; nt < 4; nt++) {
    const int col = 64 * hh + 16 * nt + l15;
    const float bv = bias[col];
#pragma unroll
    for (int i = 0; i < 4; i++) {
      const int row = row0 + 16 * g + 4 * l4 + i;
      if (row < M) C[(size_t)row * 128 + col] = acc[nt][i] + bv;
    }
  }
}

// ---------------- counting sort of idx_ji (per-call, idempotent) ----------------
__global__ void hist_k(const int* __restrict__ ji, int* __restrict__ cnt, int T) {
  int t = blockIdx.x * 256 + threadIdx.x;
  const int stride = gridDim.x * 256;
  for (; t < T; t += stride) atomicAdd(&cnt[ji[t]], 1);
}

__global__ void scan1_k(const int* __restrict__ cnt, int* __restrict__ csum, int E) {
  __shared__ int red[256];
  const int c0 = blockIdx.x * 2048;
  int s = 0;
  for (int i = threadIdx.x; i < 2048; i += 256) {
    int e = c0 + i;
    if (e < E) s += cnt[e];
  }
  red[threadIdx.x] = s;
  __syncthreads();
  for (int o = 128; o > 0; o >>= 1) {
    if (threadIdx.x < o) red[threadIdx.x] += red[threadIdx.x + o];
    __syncthreads();
  }
  if (threadIdx.x == 0) csum[blockIdx.x] = red[0];
}

__global__ void scan2_k(int* __restrict__ csum, int n) {
  if (threadIdx.x == 0 && blockIdx.x == 0) {
    int acc = 0;
    for (int i = 0; i < n; i++) { int v = csum[i]; csum[i] = acc; acc += v; }
  }
}

__global__ void scan3_k(const int* __restrict__ cnt, const int* __restrict__ csum,
                        int* __restrict__ off, int E) {
  __shared__ int ts[256];
  const int c0 = blockIdx.x * 2048;
  const int tid = threadIdx.x;
  int loc[8];
  int s = 0;
#pragma unroll
  for (int k = 0; k < 8; k++) {
    int e = c0 + tid * 8 + k;
    loc[k] = (e < E) ? cnt[e] : 0;
    s += loc[k];
  }
  ts[tid] = s;
  __syncthreads();
  for (int o = 1; o < 256; o <<= 1) {
    int v = (tid >= o) ? ts[tid - o] : 0;
    __syncthreads();
    ts[tid] += v;
    __syncthreads();
  }
  int base = csum[blockIdx.x] + ((tid > 0) ? ts[tid - 1] : 0);
#pragma unroll
  for (int k = 0; k < 8; k++) {
    int e = c0 + tid * 8 + k;
    if (e < E) { off[e] = base; base += loc[k]; }
  }
}

__global__ void scatter_k(const int* __restrict__ ji, int* __restrict__ cursor,
                          int* __restrict__ perm, int T) {
  int t = blockIdx.x * 256 + threadIdx.x;
  const int stride = gridDim.x * 256;
  for (; t < T; t += stride) {
    int e = ji[t];
    int p = atomicAdd(&cursor[e], 1);
    perm[p] = t;
  }
}

// ---------------- fused triplet kernel (sorted order) ----------------
struct G12 {
  short8 a0, a1;          // h[ki] 16 bf16
  short8 b0, b1;          // h[ji] 16 bf16
  float4 m0, m1, m2, m3;  // M row 16 f32
};

__device__ __forceinline__ void issue12(G12& g, const unsigned short* __restrict__ fa,
                                        const unsigned short* __restrict__ fb,
                                        const float* __restrict__ mm, int cseg)
{
  g.a0 = *(const short8*)(fa + cseg);
  g.a1 = *(const short8*)(fa + cseg + 8);
  g.b0 = *(const short8*)(fb + cseg);
  g.b1 = *(const short8*)(fb + cseg + 8);
  g.m0 = *(const float4*)(mm + cseg + 0);
  g.m1 = *(const float4*)(mm + cseg + 4);
  g.m2 = *(const float4*)(mm + cseg + 8);
  g.m3 = *(const float4*)(mm + cseg + 12);
}

__device__ __forceinline__ void pack8x(const short8& a, const short8& b,
                                       const float4& m0, const float4& m1, short8& o)
{
  float p[8];
  p[0] = bf2f((unsigned short)a[0]) * m0.x * bf2f((unsigned short)b[0]);
  p[1] = bf2f((unsigned short)a[1]) * m0.y * bf2f((unsigned short)b[1]);
  p[2] = bf2f((unsigned short)a[2]) * m0.z * bf2f((unsigned short)b[2]);
  p[3] = bf2f((unsigned short)a[3]) * m0.w * bf2f((unsigned short)b[3]);
  p[4] = bf2f((unsigned short)a[4]) * m1.x * bf2f((unsigned short)b[4]);
  p[5] = bf2f((unsigned short)a[5]) * m1.y * bf2f((unsigned short)b[5]);
  p[6] = bf2f((unsigned short)a[6]) * m1.z * bf2f((unsigned short)b[6]);
  p[7] = bf2f((unsigned short)a[7]) * m1.w * bf2f((unsigned short)b[7]);
  union { short8 s; unsigned u[4]; } t;
  t.u[0] = cvtpk_bf16(p[0], p[1]);
  t.u[1] = cvtpk_bf16(p[2], p[3]);
  t.u[2] = cvtpk_bf16(p[4], p[5]);
  t.u[3] = cvtpk_bf16(p[6], p[7]);
  o = t.s;
}

__device__ __forceinline__ void pack16(const G12& g, short8& lo, short8& hi)
{
  pack8x(g.a0, g.b0, g.m0, g.m1, lo);
  pack8x(g.a1, g.b1, g.m2, g.m3, hi);
}

__device__ __forceinline__ void writep(unsigned short* pb, int r, int cseg,
                                       const short8& lo, const short8& hi)
{
  const int c0 = cseg >> 3;
  *(short8*)(pb + r * 128 + (((c0) ^ (r & 7)) << 3)) = lo;
  *(short8*)(pb + r * 128 + (((c0 + 1) ^ (r & 7)) << 3)) = hi;
}

__device__ __forceinline__ void mfma_block4(const unsigned short* abuf,
                                            const unsigned short* wsT,
                                            f32x4 (&acc)[4],
                                            int g, int hh, int l15, int l4)
{
  const int arow = 16 * g + l15;
  __builtin_amdgcn_s_setprio(1);
#pragma unroll
  for (int ks = 0; ks < 4; ks++) {
    short8 a = *(const short8*)(abuf + arow * 128 + (((4 * ks + l4) ^ (arow & 7)) << 3));
#pragma unroll
    for (int ct = 0; ct < 4; ct++) {
      const int col = 64 * hh + 16 * ct + l15;
      short8 b = *(const short8*)(wsT + col * 128 + (((4 * ks + l4) ^ (col & 7)) << 3));
      acc[ct] = __builtin_amdgcn_mfma_f32_16x16x32_bf16(a, b, acc[ct], 0, 0, 0);
    }
  }
  __builtin_amdgcn_s_setprio(0);
}

__device__ __forceinline__ void store_s(unsigned short* pbuf, const f32x4 (&acc)[4],
                                        const float* __restrict__ bias,
                                        int g, int hh, int l15, int l4)
{
#pragma unroll
  for (int ct = 0; ct < 4; ct++) {
    const int col = 64 * hh + 16 * ct + l15;
    const float bv = bias[col];
#pragma unroll
    for (int i = 0; i < 4; i++) {
      const int r = 16 * g + 4 * l4 + i;
      float v = silu_f(acc[ct][i] + bv);
      pbuf[r * 128 + ((((col >> 3) ^ (r & 7)) << 3)) + (col & 7)] = f2bf(v);
    }
  }
}

// Assumes T % 64 == 0 (T = 1e6 -> 15625 tiles exactly).
__global__ __launch_bounds__(512, 2)
void triplet_fused(const unsigned short* __restrict__ h,
                   const float* __restrict__ M01, const float* __restrict__ M02,
                   const float* __restrict__ Ws01, const float* __restrict__ bs01,
                   const float* __restrict__ Ws02, const float* __restrict__ bs02,
                   const float* __restrict__ Ws,   const float* __restrict__ bs,
                   const int* __restrict__ idx_ji, const int* __restrict__ idx_ki,
                   const int* __restrict__ perm,
                   float* __restrict__ out_acc, int T)
{
  __shared__ unsigned short wsT01[128 * 128];  // 32 KB
  __shared__ unsigned short wsT02[128 * 128];  // 32 KB
  __shared__ unsigned short wsTA[128 * 128];   // 32 KB (Ws rows 0..127)
  __shared__ unsigned short wsTB[128 * 128];   // 32 KB (Ws rows 128..255)
  __shared__ unsigned short pbA[64 * 128];     // 16 KB: p01/p02, then poolA f32[64][64]
  __shared__ unsigned short pbB[64 * 128];     // 16 KB: s01/s02, then poolB f32[64][64]
  float* const poolA = (float*)pbA;
  float* const poolB = (float*)pbB;

  const int tid = threadIdx.x;

  for (int e = tid; e < 128 * 128; e += 512) {
    const int k = e >> 7, n = e & 127;
    const int d = n * 128 + ((((k >> 3) ^ (n & 7)) << 3)) + (k & 7);
    wsT01[d] = f2bf(Ws01[e]);
    wsT02[d] = f2bf(Ws02[e]);
    wsTA[d]  = f2bf(Ws[e]);
    wsTB[d]  = f2bf(Ws[128 * 128 + e]);
  }
  __syncthreads();

  const int lane = tid & 63;
  const int wv = tid >> 6;
  const int g = wv & 3;        // row group (16 rows)
  const int hh = wv >> 2;      // col half (64 cols)
  const int l15 = lane & 15, l4 = lane >> 4;
  const f32x4 zero4 = {0.f, 0.f, 0.f, 0.f};

  const int r = tid >> 3;           // gather row 0..63
  const int cseg = (tid & 7) * 16;  // 16 cols per thread
  const int ntiles = T >> 6;

  int tile = blockIdx.x;
  if (tile >= ntiles) return;

  // prologue: first tile's p01 inputs
  int trow = perm[tile * 64 + r];
  int ek = idx_ki[trow], ej = idx_ji[trow];
  short8 p01lo, p01hi;
  {
    G12 g1;
    issue12(g1, h + (size_t)ek * 256, h + (size_t)ej * 256,
            M01 + (size_t)trow * 128, cseg);
    pack16(g1, p01lo, p01hi);
  }

  for (; tile < ntiles; tile += gridDim.x) {
    const int rbase = tile << 6;
    f32x4 acc3[4] = {zero4, zero4, zero4, zero4};

    // ---- P1: write p01 -> pbA ; issue p02 loads ----
    writep(pbA, r, cseg, p01lo, p01hi);
    G12 g2;
    issue12(g2, h + (size_t)ek * 256 + 128, h + (size_t)ej * 256 + 128,
            M02 + (size_t)trow * 128, cseg);
    const int pj = perm[rbase + lane];   // sorted row `lane` of this tile
    TSYNC();

    // ---- P2: MFMA1 -> s01 -> pbB ; next-tile idx prefetch ----
    int srow_n = (tile + gridDim.x) * 64 + r;
    if (srow_n >= T) srow_n = T - 1;
    const int trow_n = perm[srow_n];
    const int ekn = idx_ki[trow_n], ejn = idx_ji[trow_n];
    const int jrv = idx_ji[pj];          // this tile's edge id for row `lane`
    {
      f32x4 acc1[4] = {zero4, zero4, zero4, zero4};
      mfma_block4(pbA, wsT01, acc1, g, hh, l15, l4);
      store_s(pbB, acc1, bs01, g, hh, l15, l4);
    }
    TSYNC();

    // ---- P3: MFMA2 (s01,WsA)->acc3 ; pack p02 -> pbA ----
    mfma_block4(pbB, wsTA, acc3, g, hh, l15, l4);
    {
      short8 lo, hi;
      pack16(g2, lo, hi);
      writep(pbA, r, cseg, lo, hi);
    }
    TSYNC();

    // ---- P4: issue next p01 ; MFMA3 -> s02 -> pbB ----
    G12 g1n;
    issue12(g1n, h + (size_t)ekn * 256, h + (size_t)ejn * 256,
            M01 + (size_t)trow_n * 128, cseg);
    {
      f32x4 acc2[4] = {zero4, zero4, zero4, zero4};
      mfma_block4(pbA, wsT02, acc2, g, hh, l15, l4);
      store_s(pbB, acc2, bs02, g, hh, l15, l4);
    }
    TSYNC();

    // ---- P5: MFMA4 (s02,WsB)->acc3 ----
    mfma_block4(pbB, wsTB, acc3, g, hh, l15, l4);
    TSYNC();

    // ---- P6: sfin = silu(acc3+bs) f32 -> poolA/poolB ----
    {
      float* const pool = hh ? poolB : poolA;
#pragma unroll
      for (int ct = 0; ct < 4; ct++) {
        const float bv = bs[64 * hh + 16 * ct + l15];
#pragma unroll
        for (int i = 0; i < 4; i++)
          pool[(16 * g + 4 * l4 + i) * 64 + 16 * ct + l15] = silu_f(acc3[ct][i] + bv);
      }
    }
    TSYNC();

    // ---- P7: segment-sum over sorted rows; store interior, atomic boundary ----
    {
      const int jprev = __shfl_up(jrv, 1, 64);
      const bool isst = (lane == 0) || (jrv != jprev);
      unsigned long long mask = __ballot(isst);
      const int nseg = __popcll(mask);
      for (int s = wv; s < nseg; s += 8) {
        unsigned long long m2 = mask;
        for (int d = 0; d < s; d++) m2 &= m2 - 1;   // drop s lowest set bits
        const int fr = __ffsll(m2) - 1;
        unsigned long long m3 = m2 & (m2 - 1);
        const int lr = m3 ? (__ffsll(m3) - 2) : 63;
        const int e = __shfl(jrv, fr, 64);
        float s0 = 0.f, s1 = 0.f;
        for (int rr = fr; rr <= lr; ++rr) {
          s0 += poolA[rr * 64 + lane];
          s1 += poolB[rr * 64 + lane];
        }
        float* dst = out_acc + (size_t)e * 128;
        if (fr == 0 || lr == 63) {
          atomicAdd(dst + lane, s0);
          atomicAdd(dst + 64 + lane, s1);
        } else {
          dst[lane] = s0;
          dst[64 + lane] = s1;
        }
      }
    }
    // pack next tile's p01 late (loads have had P4..P7 to land)
    pack16(g1n, p01lo, p01hi);
    ek = ekn; ej = ejn; trow = trow_n;
    TSYNC();  // pool reads done before next tile's P1 overwrites pbA
  }
}

extern "C" void kernel_launch(void* const* d_in, const int* in_sizes, int n_in,
                              void* d_out, int out_size, void* d_ws, size_t ws_size,
                              hipStream_t stream)
{
  const float* f    = (const float*)d_in[0];
  const float* M01  = (const float*)d_in[1];
  const float* M02  = (const float*)d_in[2];
  const float* W1   = (const float*)d_in[3];
  const float* b1   = (const float*)d_in[4];
  const float* W2   = (const float*)d_in[5];
  const float* b2   = (const float*)d_in[6];
  const float* Ws01 = (const float*)d_in[7];
  const float* bs01 = (const float*)d_in[8];
  const float* Ws02 = (const float*)d_in[9];
  const float* bs02 = (const float*)d_in[10];
  const float* Ws   = (const float*)d_in[11];
  const float* bs   = (const float*)d_in[12];
  const float* Wout = (const float*)d_in[13];
  const float* bout = (const float*)d_in[14];
  const int* idx_ji = (const int*)d_in[16];
  const int* idx_ki = (const int*)d_in[17];

  const int E = in_sizes[0] / 256;
  const int T = in_sizes[1] / 128;

  // ws layout
  char* w = (char*)d_ws;
  unsigned short* hbuf = (unsigned short*)w;                       // [E][256] bf16
  size_t o = ((size_t)E * 256 * 2 + 255) & ~(size_t)255;
  unsigned short* wt1h = (unsigned short*)(w + o); o += 256 * 256 * 2;
  unsigned short* wt1l = (unsigned short*)(w + o); o += 256 * 256 * 2;
  unsigned short* wt2h = (unsigned short*)(w + o); o += 256 * 256 * 2;
  unsigned short* wt2l = (unsigned short*)(w + o); o += 256 * 256 * 2;
  unsigned short* wtoh = (unsigned short*)(w + o); o += 128 * 128 * 2;
  unsigned short* wtol = (unsigned short*)(w + o); o += 128 * 128 * 2;
  o = (o + 255) & ~(size_t)255;
  int* cnt = (int*)(w + o);  o += ((size_t)E * 4 + 255) & ~(size_t)255;
  int* off = (int*)(w + o);  o += ((size_t)E * 4 + 255) & ~(size_t)255;
  int* csum = (int*)(w + o); o += 4096;
  int* perm = (int*)(w + o);                                       // [T]

  float* out_acc = (float*)d_out;

  const int mb = (E + 63) / 64;

  // weight prep (tiny)
  prep_w<<<(256 * 256 + 255) / 256, 256, 0, stream>>>(W1, wt1h, wt1l, 256, 256);
  prep_w<<<(256 * 256 + 255) / 256, 256, 0, stream>>>(W2, wt2h, wt2l, 256, 256);
  prep_w<<<(128 * 128 + 255) / 256, 256, 0, stream>>>(Wout, wtoh, wtol, 128, 128);

  // edge MLP via split-bf16 MFMA: h1 = silu(f@W1+b1); h = silu(h1@W2+b2) (in-place)
  mlp_gemm<0, 1><<<mb, 512, 0, stream>>>(f, wt1h, wt1l, b1, hbuf, E);
  mlp_gemm<1, 0><<<mb, 512, 0, stream>>>(hbuf, wt2h, wt2l, b2, hbuf, E);

  // counting sort of idx_ji -> perm (recomputed every call; graph-replay safe)
  hipMemsetAsync(cnt, 0, (size_t)E * 4, stream);
  hist_k<<<1024, 256, 0, stream>>>(idx_ji, cnt, T);
  const int nchunks = (E + 2047) / 2048;
  scan1_k<<<nchunks, 256, 0, stream>>>(cnt, csum, E);
  scan2_k<<<1, 64, 0, stream>>>(csum, nchunks);
  scan3_k<<<nchunks, 256, 0, stream>>>(cnt, csum, off, E);
  scatter_k<<<1024, 256, 0, stream>>>(idx_ji, off, perm, T);

  hipMemsetAsync(d_out, 0, (size_t)E * 128 * sizeof(float), stream);

  const int ntiles = (T + 63) / 64;
  const int grid = ntiles < 256 ? ntiles : 256;  // persistent, 1 block/CU
  triplet_fused<<<grid, 512, 0, stream>>>(hbuf, M01, M02, Ws01, bs01, Ws02, bs02,
                                          Ws, bs, idx_ji, idx_ki, perm, out_acc, T);

  // out = out_acc @ Wout + bout (in-place on d_out, split-bf16 3-term)
  final_gemm<<<mb, 512, 0, stream>>>(out_acc, wtoh, wtol, bout, out_acc, E);
}

// Round 7
// 962.166 us; speedup vs baseline: 1.4343x; 1.0275x over previous
//
#include <hip/hip_runtime.h>

typedef __attribute__((ext_vector_type(8))) short short8;
typedef __attribute__((ext_vector_type(4))) float f32x4;

__device__ __forceinline__ float silu_f(float x) { return x / (1.0f + __expf(-x)); }

__device__ __forceinline__ unsigned short f2bf(float x) {
  unsigned u = __float_as_uint(x);
  u += 0x7FFFu + ((u >> 16) & 1u);
  return (unsigned short)(u >> 16);
}
__device__ __forceinline__ float bf2f(unsigned short v) {
  return __uint_as_float(((unsigned)v) << 16);
}
__device__ __forceinline__ unsigned cvtpk_bf16(float lo, float hi) {
  unsigned r;
  asm("v_cvt_pk_bf16_f32 %0, %1, %2" : "=v"(r) : "v"(lo), "v"(hi));
  return r;
}

// raw barrier: LDS writes visible, sync, do NOT drain vmcnt
#define TSYNC() do { asm volatile("s_waitcnt lgkmcnt(0)" ::: "memory"); \
                     __builtin_amdgcn_s_barrier(); \
                     asm volatile("" ::: "memory"); } while (0)

// ---------------- weight prep: W[K][N] f32 -> panel-swizzled bf16 hi/lo ----------------
__global__ void prep_w(const float* __restrict__ W, unsigned short* __restrict__ wh,
                       unsigned short* __restrict__ wl, int K, int N)
{
  int e = blockIdx.x * 256 + threadIdx.x;
  if (e >= K * N) return;
  int k = e / N, n = e % N;
  float w = W[e];
  unsigned short hi = f2bf(w);
  unsigned short lo = f2bf(w - bf2f(hi));
  int kp = k >> 6, kk = k & 63;
  size_t dst = (size_t)kp * N * 64 + (size_t)n * 64 + ((((kk >> 3) ^ (n & 7)) << 3)) + (kk & 7);
  wh[dst] = hi;
  wl[dst] = lo;
}

// ---------------- MLP GEMM: C = silu(A @ W + b), K=256, N=256, bf16 out ----------------
template<int INBF, int ASPLIT>
__global__ __launch_bounds__(512)
void mlp_gemm(const void* A_, const unsigned short* __restrict__ wh,
              const unsigned short* __restrict__ wl,
              const float* __restrict__ bias, unsigned short* __restrict__ C, int M)
{
  __shared__ unsigned short aTh[64 * 64], aTl[64 * 64];
  __shared__ unsigned short whb[256 * 64], wlb[256 * 64];
  const int tid = threadIdx.x;
  const int lane = tid & 63, wv = tid >> 6;
  const int g = wv & 3, hh = wv >> 2;
  const int l15 = lane & 15, l4 = lane >> 4;
  const int row0 = blockIdx.x * 64;
  const int r = tid >> 3, kseg = (tid & 7) * 8;
  const f32x4 zero4 = {0.f, 0.f, 0.f, 0.f};

  f32x4 acc[8];
#pragma unroll
  for (int nt = 0; nt < 8; nt++) acc[nt] = zero4;

  for (int kp = 0; kp < 4; kp++) {
    {
      const int grow = row0 + r;
      float x[8];
      if (grow < M) {
        if (INBF) {
          short8 v = *(const short8*)((const unsigned short*)A_ + (size_t)grow * 256 + kp * 64 + kseg);
#pragma unroll
          for (int j = 0; j < 8; j++) x[j] = bf2f((unsigned short)v[j]);
        } else {
          const float* ap = (const float*)A_ + (size_t)grow * 256 + kp * 64 + kseg;
          float4 v0 = *(const float4*)ap;
          float4 v1 = *(const float4*)(ap + 4);
          x[0] = v0.x; x[1] = v0.y; x[2] = v0.z; x[3] = v0.w;
          x[4] = v1.x; x[5] = v1.y; x[6] = v1.z; x[7] = v1.w;
        }
      } else {
#pragma unroll
        for (int j = 0; j < 8; j++) x[j] = 0.f;
      }
      union { short8 s; unsigned short us[8]; } H, L;
#pragma unroll
      for (int j = 0; j < 8; j++) {
        H.us[j] = f2bf(x[j]);
        L.us[j] = ASPLIT ? f2bf(x[j] - bf2f(H.us[j])) : (unsigned short)0;
      }
      const int dst = r * 64 + ((((kseg >> 3) ^ (r & 7)) << 3));
      *(short8*)(aTh + dst) = H.s;
      if (ASPLIT) *(short8*)(aTl + dst) = L.s;
    }
    {
      const short8* srcH = (const short8*)(wh + (size_t)kp * 16384);
      const short8* srcL = (const short8*)(wl + (size_t)kp * 16384);
#pragma unroll
      for (int i = 0; i < 4; i++) {
        ((short8*)whb)[tid + 512 * i] = srcH[tid + 512 * i];
        ((short8*)wlb)[tid + 512 * i] = srcL[tid + 512 * i];
      }
    }
    __syncthreads();
#pragma unroll
    for (int ks = 0; ks < 2; ks++) {
      const int arow = 16 * g + l15;
      const int aof = arow * 64 + (((4 * ks + l4) ^ (arow & 7)) << 3);
      short8 ah = *(const short8*)(aTh + aof);
      short8 al = *(const short8*)(aTl + aof);
#pragma unroll
      for (int nt = 0; nt < 8; nt++) {
        const int col = 128 * hh + 16 * nt + l15;
        const int bof = col * 64 + (((4 * ks + l4) ^ (col & 7)) << 3);
        short8 bh = *(const short8*)(whb + bof);
        short8 bl = *(const short8*)(wlb + bof);
        acc[nt] = __builtin_amdgcn_mfma_f32_16x16x32_bf16(ah, bh, acc[nt], 0, 0, 0);
        acc[nt] = __builtin_amdgcn_mfma_f32_16x16x32_bf16(ah, bl, acc[nt], 0, 0, 0);
        if (ASPLIT)
          acc[nt] = __builtin_amdgcn_mfma_f32_16x16x32_bf16(al, bh, acc[nt], 0, 0, 0);
      }
    }
    __syncthreads();
  }
#pragma unroll
  for (int nt = 0; nt < 8; nt++) {
    const int col = 128 * hh + 16 * nt + l15;
    const float bv = bias[col];
#pragma unroll
    for (int i = 0; i < 4; i++) {
      const int row = row0 + 16 * g + 4 * l4 + i;
      if (row < M) C[(size_t)row * 256 + col] = f2bf(silu_f(acc[nt][i] + bv));
    }
  }
}

// ---------------- final GEMM: C = A @ Wout + b, K=128, N=128, f32 in/out ----------------
__global__ __launch_bounds__(512)
void final_gemm(const float* __restrict__ A, const unsigned short* __restrict__ wh,
                const unsigned short* __restrict__ wl,
                const float* __restrict__ bias, float* __restrict__ C, int M)
{
  __shared__ unsigned short aTh[64 * 64], aTl[64 * 64];
  __shared__ unsigned short whb[128 * 64], wlb[128 * 64];
  const int tid = threadIdx.x;
  const int lane = tid & 63, wv = tid >> 6;
  const int g = wv & 3, hh = wv >> 2;
  const int l15 = lane & 15, l4 = lane >> 4;
  const int row0 = blockIdx.x * 64;
  const int r = tid >> 3, kseg = (tid & 7) * 8;
  const f32x4 zero4 = {0.f, 0.f, 0.f, 0.f};

  f32x4 acc[4];
#pragma unroll
  for (int nt = 0; nt < 4; nt++) acc[nt] = zero4;

  for (int kp = 0; kp < 2; kp++) {
    {
      const int grow = row0 + r;
      float x[8];
      if (grow < M) {
        const float* ap = A + (size_t)grow * 128 + kp * 64 + kseg;
        float4 v0 = *(const float4*)ap;
        float4 v1 = *(const float4*)(ap + 4);
        x[0] = v0.x; x[1] = v0.y; x[2] = v0.z; x[3] = v0.w;
        x[4] = v1.x; x[5] = v1.y; x[6] = v1.z; x[7] = v1.w;
      } else {
#pragma unroll
        for (int j = 0; j < 8; j++) x[j] = 0.f;
      }
      union { short8 s; unsigned short us[8]; } H, L;
#pragma unroll
      for (int j = 0; j < 8; j++) {
        H.us[j] = f2bf(x[j]);
        L.us[j] = f2bf(x[j] - bf2f(H.us[j]));
      }
      const int dst = r * 64 + ((((kseg >> 3) ^ (r & 7)) << 3));
      *(short8*)(aTh + dst) = H.s;
      *(short8*)(aTl + dst) = L.s;
    }
    {
      const short8* srcH = (const short8*)(wh + (size_t)kp * 8192);
      const short8* srcL = (const short8*)(wl + (size_t)kp * 8192);
#pragma unroll
      for (int i = 0; i < 2; i++) {
        ((short8*)whb)[tid + 512 * i] = srcH[tid + 512 * i];
        ((short8*)wlb)[tid + 512 * i] = srcL[tid + 512 * i];
      }
    }
    __syncthreads();
#pragma unroll
    for (int ks = 0; ks < 2; ks++) {
      const int arow = 16 * g + l15;
      const int aof = arow * 64 + (((4 * ks + l4) ^ (arow & 7)) << 3);
      short8 ah = *(const short8*)(aTh + aof);
      short8 al = *(const short8*)(aTl + aof);
#pragma unroll
      for (int nt = 0; nt < 4; nt++) {
        const int col = 64 * hh + 16 * nt + l15;
        const int bof = col * 64 + (((4 * ks + l4) ^ (col & 7)) << 3);
        short8 bh = *(const short8*)(whb + bof);
        short8 bl = *(const short8*)(wlb + bof);
        acc[nt] = __builtin_amdgcn_mfma_f32_16x16x32_bf16(ah, bh, acc[nt], 0, 0, 0);
        acc[nt] = __builtin_amdgcn_mfma_f32_16x16x32_bf16(ah, bl, acc[nt], 0, 0, 0);
        acc[nt] = __builtin_amdgcn_mfma_f32_16x16x32_bf16(al, bh, acc[nt], 0, 0, 0);
      }
    }
    __syncthreads();
  }
#pragma unroll
  for (int nt = 0; nt < 4; nt++) {
    const int col = 64 * hh + 16 * nt + l15;
    const float bv = bias[col];
#pragma unroll
    for (int i = 0; i < 4; i++) {
      const int row = row0 + 16 * g + 4 * l4 + i;
      if (row < M) C[(size_t)row * 128 + col] = acc[nt][i] + bv;
    }
  }
}

// ---------------- counting sort of idx_ji ----------------
__global__ void hist_k(const int* __restrict__ ji, int* __restrict__ cnt, int T) {
  int t = blockIdx.x * 256 + threadIdx.x;
  const int stride = gridDim.x * 256;
  for (; t < T; t += stride) atomicAdd(&cnt[ji[t]], 1);
}

__global__ void scan1_k(const int* __restrict__ cnt, int* __restrict__ csum, int E) {
  __shared__ int red[256];
  const int c0 = blockIdx.x * 2048;
  int s = 0;
  for (int i = threadIdx.x; i < 2048; i += 256) {
    int e = c0 + i;
    if (e < E) s += cnt[e];
  }
  red[threadIdx.x] = s;
  __syncthreads();
  for (int o = 128; o > 0; o >>= 1) {
    if (threadIdx.x < o) red[threadIdx.x] += red[threadIdx.x + o];
    __syncthreads();
  }
  if (threadIdx.x == 0) csum[blockIdx.x] = red[0];
}

__global__ void scan2_k(int* __restrict__ csum, int n) {
  if (threadIdx.x == 0 && blockIdx.x == 0) {
    int acc = 0;
    for (int i = 0; i < n; i++) { int v = csum[i]; csum[i] = acc; acc += v; }
  }
}

__global__ void scan3_k(const int* __restrict__ cnt, const int* __restrict__ csum,
                        int* __restrict__ off, int E) {
  __shared__ int ts[256];
  const int c0 = blockIdx.x * 2048;
  const int tid = threadIdx.x;
  int loc[8];
  int s = 0;
#pragma unroll
  for (int k = 0; k < 8; k++) {
    int e = c0 + tid * 8 + k;
    loc[k] = (e < E) ? cnt[e] : 0;
    s += loc[k];
  }
  ts[tid] = s;
  __syncthreads();
  for (int o = 1; o < 256; o <<= 1) {
    int v = (tid >= o) ? ts[tid - o] : 0;
    __syncthreads();
    ts[tid] += v;
    __syncthreads();
  }
  int base = csum[blockIdx.x] + ((tid > 0) ? ts[tid - 1] : 0);
#pragma unroll
  for (int k = 0; k < 8; k++) {
    int e = c0 + tid * 8 + k;
    if (e < E) { off[e] = base; base += loc[k]; }
  }
}

__global__ void scatter_k(const int* __restrict__ ji, int* __restrict__ cursor,
                          int* __restrict__ perm, int T) {
  int t = blockIdx.x * 256 + threadIdx.x;
  const int stride = gridDim.x * 256;
  for (; t < T; t += stride) {
    int e = ji[t];
    int p = atomicAdd(&cursor[e], 1);
    perm[p] = t;
  }
}

// ---------------- fused triplet kernel (sorted order, round-5 skeleton) ----------------
struct G12 {
  short8 a0, a1;          // h[ki] 16 bf16
  short8 b0, b1;          // h[ji] 16 bf16
  float4 m0, m1, m2, m3;  // M row 16 f32
};

__device__ __forceinline__ void issue12(G12& g, const unsigned short* __restrict__ fa,
                                        const unsigned short* __restrict__ fb,
                                        const float* __restrict__ mm, int cseg)
{
  g.a0 = *(const short8*)(fa + cseg);
  g.a1 = *(const short8*)(fa + cseg + 8);
  g.b0 = *(const short8*)(fb + cseg);
  g.b1 = *(const short8*)(fb + cseg + 8);
  g.m0 = *(const float4*)(mm + cseg + 0);
  g.m1 = *(const float4*)(mm + cseg + 4);
  g.m2 = *(const float4*)(mm + cseg + 8);
  g.m3 = *(const float4*)(mm + cseg + 12);
}

__device__ __forceinline__ void pack8x(const short8& a, const short8& b,
                                       const float4& m0, const float4& m1, short8& o)
{
  float p[8];
  p[0] = bf2f((unsigned short)a[0]) * m0.x * bf2f((unsigned short)b[0]);
  p[1] = bf2f((unsigned short)a[1]) * m0.y * bf2f((unsigned short)b[1]);
  p[2] = bf2f((unsigned short)a[2]) * m0.z * bf2f((unsigned short)b[2]);
  p[3] = bf2f((unsigned short)a[3]) * m0.w * bf2f((unsigned short)b[3]);
  p[4] = bf2f((unsigned short)a[4]) * m1.x * bf2f((unsigned short)b[4]);
  p[5] = bf2f((unsigned short)a[5]) * m1.y * bf2f((unsigned short)b[5]);
  p[6] = bf2f((unsigned short)a[6]) * m1.z * bf2f((unsigned short)b[6]);
  p[7] = bf2f((unsigned short)a[7]) * m1.w * bf2f((unsigned short)b[7]);
  union { short8 s; unsigned u[4]; } t;
  t.u[0] = cvtpk_bf16(p[0], p[1]);
  t.u[1] = cvtpk_bf16(p[2], p[3]);
  t.u[2] = cvtpk_bf16(p[4], p[5]);
  t.u[3] = cvtpk_bf16(p[6], p[7]);
  o = t.s;
}

__device__ __forceinline__ void pack16(const G12& g, short8& lo, short8& hi)
{
  pack8x(g.a0, g.b0, g.m0, g.m1, lo);
  pack8x(g.a1, g.b1, g.m2, g.m3, hi);
}

__device__ __forceinline__ void writep(unsigned short* pb, int r, int cseg,
                                       const short8& lo, const short8& hi)
{
  const int c0 = cseg >> 3;
  *(short8*)(pb + r * 128 + (((c0) ^ (r & 7)) << 3)) = lo;
  *(short8*)(pb + r * 128 + (((c0 + 1) ^ (r & 7)) << 3)) = hi;
}

// A from pbA/pbB (round-5 swizzle), B from fragment-order weight LDS:
// wF[((ctg*4 + ks)*64 + lane)*8 + j] = W[32*ks + 8*(lane>>4) + j][16*ctg + (lane&15)]
__device__ __forceinline__ void mfma_block4(const unsigned short* abuf,
                                            const unsigned short* wF,
                                            f32x4 (&acc)[4],
                                            int g, int hh, int lane, int l15, int l4)
{
  const int arow = 16 * g + l15;
  __builtin_amdgcn_s_setprio(1);
#pragma unroll
  for (int ks = 0; ks < 4; ks++) {
    short8 a = *(const short8*)(abuf + arow * 128 + (((4 * ks + l4) ^ (arow & 7)) << 3));
#pragma unroll
    for (int ct = 0; ct < 4; ct++) {
      const short8 b = *(const short8*)(wF + (((4 * hh + ct) * 4 + ks) * 64 + lane) * 8);
      acc[ct] = __builtin_amdgcn_mfma_f32_16x16x32_bf16(a, b, acc[ct], 0, 0, 0);
    }
  }
  __builtin_amdgcn_s_setprio(0);
}

__device__ __forceinline__ void store_s(unsigned short* pbuf, const f32x4 (&acc)[4],
                                        const float* __restrict__ bias,
                                        int g, int hh, int l15, int l4)
{
#pragma unroll
  for (int ct = 0; ct < 4; ct++) {
    const int col = 64 * hh + 16 * ct + l15;
    const float bv = bias[col];
#pragma unroll
    for (int i = 0; i < 4; i++) {
      const int r = 16 * g + 4 * l4 + i;
      float v = silu_f(acc[ct][i] + bv);
      pbuf[r * 128 + ((((col >> 3) ^ (r & 7)) << 3)) + (col & 7)] = f2bf(v);
    }
  }
}

// Assumes T % 64 == 0 (T = 1e6 -> 15625 tiles exactly).
__global__ __launch_bounds__(512, 2)
void triplet_fused(const unsigned short* __restrict__ h,
                   const float* __restrict__ M01, const float* __restrict__ M02,
                   const float* __restrict__ Ws01, const float* __restrict__ bs01,
                   const float* __restrict__ Ws02, const float* __restrict__ bs02,
                   const float* __restrict__ Ws,   const float* __restrict__ bs,
                   const int* __restrict__ idx_ji, const int* __restrict__ idx_ki,
                   const int* __restrict__ perm,
                   float* __restrict__ out_acc, int T)
{
  __shared__ unsigned short wF01[16384];   // 32 KB, fragment order
  __shared__ unsigned short wF02[16384];   // 32 KB
  __shared__ unsigned short wFA[16384];    // 32 KB (Ws rows 0..127)
  __shared__ unsigned short wFB[16384];    // 32 KB (Ws rows 128..255)
  __shared__ unsigned short pbA[64 * 128]; // 16 KB p-tiles
  __shared__ unsigned short pbB[64 * 128]; // 16 KB s-tiles

  const int tid = threadIdx.x;

  // fragment-order staging: e = ((ct*4+ks)*64+ln)*8+j  <-  W[32ks+8(ln>>4)+j][16ct+(ln&15)]
  for (int e = tid; e < 16384; e += 512) {
    const int j = e & 7, ln = (e >> 3) & 63, ks = (e >> 9) & 3, ct = e >> 11;
    const int col = 16 * ct + (ln & 15);
    const int k = 32 * ks + 8 * (ln >> 4) + j;
    const int src = k * 128 + col;
    wF01[e] = f2bf(Ws01[src]);
    wF02[e] = f2bf(Ws02[src]);
    wFA[e]  = f2bf(Ws[src]);
    wFB[e]  = f2bf(Ws[16384 + src]);
  }
  __syncthreads();

  const int lane = tid & 63;
  const int wv = tid >> 6;
  const int g = wv & 3;        // row group (16 rows)
  const int hh = wv >> 2;      // col half (64 cols)
  const int l15 = lane & 15, l4 = lane >> 4;
  const f32x4 zero4 = {0.f, 0.f, 0.f, 0.f};

  float bsv[4];
#pragma unroll
  for (int ct = 0; ct < 4; ct++) bsv[ct] = bs[64 * hh + 16 * ct + l15];

  const int r = tid >> 3;           // gather row 0..63
  const int cseg = (tid & 7) * 16;  // 16 cols per thread
  const int ntiles = T >> 6;

  int tile = blockIdx.x;
  if (tile >= ntiles) return;

  // prologue: first tile's p01 inputs
  int trow = perm[tile * 64 + r];
  int ek = idx_ki[trow], ej = idx_ji[trow];
  short8 p01lo, p01hi;
  {
    G12 g1;
    issue12(g1, h + (size_t)ek * 256, h + (size_t)ej * 256,
            M01 + (size_t)trow * 128, cseg);
    pack16(g1, p01lo, p01hi);
  }

  for (; tile < ntiles; tile += gridDim.x) {
    const int rbase = tile << 6;

    // ---- P1: write p01 -> pbA ; issue p02 loads ; issue pj load ----
    writep(pbA, r, cseg, p01lo, p01hi);
    G12 g2;
    issue12(g2, h + (size_t)ek * 256 + 128, h + (size_t)ej * 256 + 128,
            M02 + (size_t)trow * 128, cseg);
    const int pj = perm[rbase + 16 * g + l15];  // this wave's 16 sorted rows
    TSYNC();

    // ---- P2: MFMA1 -> s01 -> pbB ; next-tile idx prefetch ; jrv load ----
    int srow_n = (tile + gridDim.x) * 64 + r;
    if (srow_n >= T) srow_n = T - 1;
    const int trow_n = perm[srow_n];
    const int ekn = idx_ki[trow_n], ejn = idx_ji[trow_n];
    const int jrv = idx_ji[pj];                 // edge id of row (16g + l15)
    {
      f32x4 acc1[4] = {zero4, zero4, zero4, zero4};
      mfma_block4(pbA, wF01, acc1, g, hh, lane, l15, l4);
      store_s(pbB, acc1, bs01, g, hh, l15, l4);
    }
    TSYNC();

    // ---- P3: MFMA2 (s01,WsA)->acc3 ; pack p02 -> pbA ----
    f32x4 acc3[4] = {zero4, zero4, zero4, zero4};
    mfma_block4(pbB, wFA, acc3, g, hh, lane, l15, l4);
    {
      short8 lo, hi;
      pack16(g2, lo, hi);
      writep(pbA, r, cseg, lo, hi);
    }
    TSYNC();

    // ---- P4: issue next p01 ; MFMA3 -> s02 -> pbB ----
    G12 g1n;
    issue12(g1n, h + (size_t)ekn * 256, h + (size_t)ejn * 256,
            M01 + (size_t)trow_n * 128, cseg);
    {
      f32x4 acc2[4] = {zero4, zero4, zero4, zero4};
      mfma_block4(pbA, wF02, acc2, g, hh, lane, l15, l4);
      store_s(pbB, acc2, bs02, g, hh, l15, l4);
    }
    TSYNC();

    // ---- P5: MFMA4 (s02,WsB)->acc3 ; register segment-sum ; stores ----
    mfma_block4(pbB, wFB, acc3, g, hh, lane, l15, l4);
    {
      float sf[4][4];
#pragma unroll
      for (int ct = 0; ct < 4; ct++)
#pragma unroll
        for (int i = 0; i < 4; i++)
          sf[ct][i] = silu_f(acc3[ct][i] + bsv[ct]);

      const int ejp = __shfl_up(jrv, 1, 16);
      unsigned bm = (unsigned)(__ballot((l15 > 0) && (jrv != ejp)) & 0xFFFFull);
      int fr = 0;
      unsigned rem = bm;
      while (fr < 16) {
        const int nxt = rem ? (__ffs(rem) - 1) : 16;
        rem &= rem - 1;
        const int lr = nxt - 1;
        const int e = __shfl(jrv, fr, 16);
        float sv[4];
#pragma unroll
        for (int ct = 0; ct < 4; ct++) {
          float s = 0.f;
#pragma unroll
          for (int i = 0; i < 4; i++) {
            const int rr = 4 * l4 + i;
            s += (rr >= fr && rr <= lr) ? sf[ct][i] : 0.f;
          }
          s += __shfl_xor(s, 16);
          s += __shfl_xor(s, 32);
          sv[ct] = s;
        }
        const float s0 = (l4 == 0) ? sv[0] : (l4 == 1) ? sv[1] : (l4 == 2) ? sv[2] : sv[3];
        float* dst = out_acc + (size_t)e * 128 + 64 * hh + 16 * l4 + l15;
        if (fr == 0 || lr == 15) atomicAdd(dst, s0);  // run may continue outside this 16-row subwindow
        else *dst = s0;                               // run strictly interior -> exclusive
        fr = nxt;
      }
    }
    // pack next tile's p01 late (loads have had P4..P5 to land)
    pack16(g1n, p01lo, p01hi);
    ek = ekn; ej = ejn; trow = trow_n;
    TSYNC();  // pbB reads (MFMA4) done before next tile's P2 writes
  }
}

extern "C" void kernel_launch(void* const* d_in, const int* in_sizes, int n_in,
                              void* d_out, int out_size, void* d_ws, size_t ws_size,
                              hipStream_t stream)
{
  const float* f    = (const float*)d_in[0];
  const float* M01  = (const float*)d_in[1];
  const float* M02  = (const float*)d_in[2];
  const float* W1   = (const float*)d_in[3];
  const float* b1   = (const float*)d_in[4];
  const float* W2   = (const float*)d_in[5];
  const float* b2   = (const float*)d_in[6];
  const float* Ws01 = (const float*)d_in[7];
  const float* bs01 = (const float*)d_in[8];
  const float* Ws02 = (const float*)d_in[9];
  const float* bs02 = (const float*)d_in[10];
  const float* Ws   = (const float*)d_in[11];
  const float* bs   = (const float*)d_in[12];
  const float* Wout = (const float*)d_in[13];
  const float* bout = (const float*)d_in[14];
  const int* idx_ji = (const int*)d_in[16];
  const int* idx_ki = (const int*)d_in[17];

  const int E = in_sizes[0] / 256;
  const int T = in_sizes[1] / 128;

  char* w = (char*)d_ws;
  unsigned short* hbuf = (unsigned short*)w;                       // [E][256] bf16
  size_t o = ((size_t)E * 256 * 2 + 255) & ~(size_t)255;
  unsigned short* wt1h = (unsigned short*)(w + o); o += 256 * 256 * 2;
  unsigned short* wt1l = (unsigned short*)(w + o); o += 256 * 256 * 2;
  unsigned short* wt2h = (unsigned short*)(w + o); o += 256 * 256 * 2;
  unsigned short* wt2l = (unsigned short*)(w + o); o += 256 * 256 * 2;
  unsigned short* wtoh = (unsigned short*)(w + o); o += 128 * 128 * 2;
  unsigned short* wtol = (unsigned short*)(w + o); o += 128 * 128 * 2;
  o = (o + 255) & ~(size_t)255;
  int* cnt = (int*)(w + o);  o += ((size_t)E * 4 + 255) & ~(size_t)255;
  int* off = (int*)(w + o);  o += ((size_t)E * 4 + 255) & ~(size_t)255;
  int* csum = (int*)(w + o); o += 4096;
  int* perm = (int*)(w + o);                                       // [T]

  float* out_acc = (float*)d_out;
  const int mb = (E + 63) / 64;

  prep_w<<<(256 * 256 + 255) / 256, 256, 0, stream>>>(W1, wt1h, wt1l, 256, 256);
  prep_w<<<(256 * 256 + 255) / 256, 256, 0, stream>>>(W2, wt2h, wt2l, 256, 256);
  prep_w<<<(128 * 128 + 255) / 256, 256, 0, stream>>>(Wout, wtoh, wtol, 128, 128);

  mlp_gemm<0, 1><<<mb, 512, 0, stream>>>(f, wt1h, wt1l, b1, hbuf, E);
  mlp_gemm<1, 0><<<mb, 512, 0, stream>>>(hbuf, wt2h, wt2l, b2, hbuf, E);

  hipMemsetAsync(cnt, 0, (size_t)E * 4, stream);
  hist_k<<<1024, 256, 0, stream>>>(idx_ji, cnt, T);
  const int nchunks = (E + 2047) / 2048;
  scan1_k<<<nchunks, 256, 0, stream>>>(cnt, csum, E);
  scan2_k<<<1, 64, 0, stream>>>(csum, nchunks);
  scan3_k<<<nchunks, 256, 0, stream>>>(cnt, csum, off, E);
  scatter_k<<<1024, 256, 0, stream>>>(idx_ji, off, perm, T);

  hipMemsetAsync(d_out, 0, (size_t)E * 128 * sizeof(float), stream);

  const int ntiles = (T + 63) / 64;
  const int grid = ntiles < 256 ? ntiles : 256;  // persistent, 1 block/CU
  triplet_fused<<<grid, 512, 0, stream>>>(hbuf, M01, M02, Ws01, bs01, Ws02, bs02,
                                          Ws, bs, idx_ji, idx_ki, perm, out_acc, T);

  final_gemm<<<mb, 512, 0, stream>>>(out_acc, wtoh, wtol, bout, out_acc, E);
}

// Round 8
// 940.756 us; speedup vs baseline: 1.4670x; 1.0228x over previous
//
#include <hip/hip_runtime.h>

typedef __attribute__((ext_vector_type(8))) short short8;
typedef __attribute__((ext_vector_type(4))) float f32x4;

__device__ __forceinline__ float silu_f(float x) { return x / (1.0f + __expf(-x)); }

__device__ __forceinline__ unsigned short f2bf(float x) {
  unsigned u = __float_as_uint(x);
  u += 0x7FFFu + ((u >> 16) & 1u);
  return (unsigned short)(u >> 16);
}
__device__ __forceinline__ float bf2f(unsigned short v) {
  return __uint_as_float(((unsigned)v) << 16);
}
__device__ __forceinline__ unsigned cvtpk_bf16(float lo, float hi) {
  unsigned r;
  asm("v_cvt_pk_bf16_f32 %0, %1, %2" : "=v"(r) : "v"(lo), "v"(hi));
  return r;
}

// raw barrier: LDS writes visible, sync, do NOT drain vmcnt
#define TSYNC() do { asm volatile("s_waitcnt lgkmcnt(0)" ::: "memory"); \
                     __builtin_amdgcn_s_barrier(); \
                     asm volatile("" ::: "memory"); } while (0)

// ---------------- weight prep (fused): W[K][N] f32 -> panel-swizzled bf16 hi/lo ----------------
__device__ __forceinline__ void prep_one(const float* __restrict__ W,
                                         unsigned short* __restrict__ wh,
                                         unsigned short* __restrict__ wl,
                                         int N, int e)
{
  int k = e / N, n = e % N;
  float w = W[e];
  unsigned short hi = f2bf(w);
  unsigned short lo = f2bf(w - bf2f(hi));
  int kp = k >> 6, kk = k & 63;
  size_t dst = (size_t)kp * N * 64 + (size_t)n * 64 + ((((kk >> 3) ^ (n & 7)) << 3)) + (kk & 7);
  wh[dst] = hi;
  wl[dst] = lo;
}

__global__ void prep_all(const float* __restrict__ W1, unsigned short* w1h, unsigned short* w1l,
                         const float* __restrict__ W2, unsigned short* w2h, unsigned short* w2l,
                         const float* __restrict__ Wo, unsigned short* woh, unsigned short* wol)
{
  int e = blockIdx.x * 256 + threadIdx.x;
  if (e < 256 * 256) {
    prep_one(W1, w1h, w1l, 256, e);
    prep_one(W2, w2h, w2l, 256, e);
  }
  if (e < 128 * 128) prep_one(Wo, woh, wol, 128, e);
}

// ---------------- MLP GEMM: C = silu(A @ W + b), K=256, N=256, bf16 out ----------------
template<int INBF, int ASPLIT>
__global__ __launch_bounds__(512)
void mlp_gemm(const void* A_, const unsigned short* __restrict__ wh,
              const unsigned short* __restrict__ wl,
              const float* __restrict__ bias, unsigned short* __restrict__ C, int M)
{
  __shared__ unsigned short aTh[64 * 64], aTl[64 * 64];
  __shared__ unsigned short whb[256 * 64], wlb[256 * 64];
  const int tid = threadIdx.x;
  const int lane = tid & 63, wv = tid >> 6;
  const int g = wv & 3, hh = wv >> 2;
  const int l15 = lane & 15, l4 = lane >> 4;
  const int row0 = blockIdx.x * 64;
  const int r = tid >> 3, kseg = (tid & 7) * 8;
  const f32x4 zero4 = {0.f, 0.f, 0.f, 0.f};

  f32x4 acc[8];
#pragma unroll
  for (int nt = 0; nt < 8; nt++) acc[nt] = zero4;

  for (int kp = 0; kp < 4; kp++) {
    {
      const int grow = row0 + r;
      float x[8];
      if (grow < M) {
        if (INBF) {
          short8 v = *(const short8*)((const unsigned short*)A_ + (size_t)grow * 256 + kp * 64 + kseg);
#pragma unroll
          for (int j = 0; j < 8; j++) x[j] = bf2f((unsigned short)v[j]);
        } else {
          const float* ap = (const float*)A_ + (size_t)grow * 256 + kp * 64 + kseg;
          float4 v0 = *(const float4*)ap;
          float4 v1 = *(const float4*)(ap + 4);
          x[0] = v0.x; x[1] = v0.y; x[2] = v0.z; x[3] = v0.w;
          x[4] = v1.x; x[5] = v1.y; x[6] = v1.z; x[7] = v1.w;
        }
      } else {
#pragma unroll
        for (int j = 0; j < 8; j++) x[j] = 0.f;
      }
      union { short8 s; unsigned short us[8]; } H, L;
#pragma unroll
      for (int j = 0; j < 8; j++) {
        H.us[j] = f2bf(x[j]);
        L.us[j] = ASPLIT ? f2bf(x[j] - bf2f(H.us[j])) : (unsigned short)0;
      }
      const int dst = r * 64 + ((((kseg >> 3) ^ (r & 7)) << 3));
      *(short8*)(aTh + dst) = H.s;
      if (ASPLIT) *(short8*)(aTl + dst) = L.s;
    }
    {
      const short8* srcH = (const short8*)(wh + (size_t)kp * 16384);
      const short8* srcL = (const short8*)(wl + (size_t)kp * 16384);
#pragma unroll
      for (int i = 0; i < 4; i++) {
        ((short8*)whb)[tid + 512 * i] = srcH[tid + 512 * i];
        ((short8*)wlb)[tid + 512 * i] = srcL[tid + 512 * i];
      }
    }
    __syncthreads();
#pragma unroll
    for (int ks = 0; ks < 2; ks++) {
      const int arow = 16 * g + l15;
      const int aof = arow * 64 + (((4 * ks + l4) ^ (arow & 7)) << 3);
      short8 ah = *(const short8*)(aTh + aof);
      short8 al = *(const short8*)(aTl + aof);
#pragma unroll
      for (int nt = 0; nt < 8; nt++) {
        const int col = 128 * hh + 16 * nt + l15;
        const int bof = col * 64 + (((4 * ks + l4) ^ (col & 7)) << 3);
        short8 bh = *(const short8*)(whb + bof);
        short8 bl = *(const short8*)(wlb + bof);
        acc[nt] = __builtin_amdgcn_mfma_f32_16x16x32_bf16(ah, bh, acc[nt], 0, 0, 0);
        acc[nt] = __builtin_amdgcn_mfma_f32_16x16x32_bf16(ah, bl, acc[nt], 0, 0, 0);
        if (ASPLIT)
          acc[nt] = __builtin_amdgcn_mfma_f32_16x16x32_bf16(al, bh, acc[nt], 0, 0, 0);
      }
    }
    __syncthreads();
  }
#pragma unroll
  for (int nt = 0; nt < 8; nt++) {
    const int col = 128 * hh + 16 * nt + l15;
    const float bv = bias[col];
#pragma unroll
    for (int i = 0; i < 4; i++) {
      const int row = row0 + 16 * g + 4 * l4 + i;
      if (row < M) C[(size_t)row * 256 + col] = f2bf(silu_f(acc[nt][i] + bv));
    }
  }
}

// ---------------- final GEMM: C = A @ Wout + b, K=128, N=128, f32 in/out ----------------
__global__ __launch_bounds__(512)
void final_gemm(const float* __restrict__ A, const unsigned short* __restrict__ wh,
                const unsigned short* __restrict__ wl,
                const float* __restrict__ bias, float* __restrict__ C, int M)
{
  __shared__ unsigned short aTh[64 * 64], aTl[64 * 64];
  __shared__ unsigned short whb[128 * 64], wlb[128 * 64];
  const int tid = threadIdx.x;
  const int lane = tid & 63, wv = tid >> 6;
  const int g = wv & 3, hh = wv >> 2;
  const int l15 = lane & 15, l4 = lane >> 4;
  const int row0 = blockIdx.x * 64;
  const int r = tid >> 3, kseg = (tid & 7) * 8;
  const f32x4 zero4 = {0.f, 0.f, 0.f, 0.f};

  f32x4 acc[4];
#pragma unroll
  for (int nt = 0; nt < 4; nt++) acc[nt] = zero4;

  for (int kp = 0; kp < 2; kp++) {
    {
      const int grow = row0 + r;
      float x[8];
      if (grow < M) {
        const float* ap = A + (size_t)grow * 128 + kp * 64 + kseg;
        float4 v0 = *(const float4*)ap;
        float4 v1 = *(const float4*)(ap + 4);
        x[0] = v0.x; x[1] = v0.y; x[2] = v0.z; x[3] = v0.w;
        x[4] = v1.x; x[5] = v1.y; x[6] = v1.z; x[7] = v1.w;
      } else {
#pragma unroll
        for (int j = 0; j < 8; j++) x[j] = 0.f;
      }
      union { short8 s; unsigned short us[8]; } H, L;
#pragma unroll
      for (int j = 0; j < 8; j++) {
        H.us[j] = f2bf(x[j]);
        L.us[j] = f2bf(x[j] - bf2f(H.us[j]));
      }
      const int dst = r * 64 + ((((kseg >> 3) ^ (r & 7)) << 3));
      *(short8*)(aTh + dst) = H.s;
      *(short8*)(aTl + dst) = L.s;
    }
    {
      const short8* srcH = (const short8*)(wh + (size_t)kp * 8192);
      const short8* srcL = (const short8*)(wl + (size_t)kp * 8192);
#pragma unroll
      for (int i = 0; i < 2; i++) {
        ((short8*)whb)[tid + 512 * i] = srcH[tid + 512 * i];
        ((short8*)wlb)[tid + 512 * i] = srcL[tid + 512 * i];
      }
    }
    __syncthreads();
#pragma unroll
    for (int ks = 0; ks < 2; ks++) {
      const int arow = 16 * g + l15;
      const int aof = arow * 64 + (((4 * ks + l4) ^ (arow & 7)) << 3);
      short8 ah = *(const short8*)(aTh + aof);
      short8 al = *(const short8*)(aTl + aof);
#pragma unroll
      for (int nt = 0; nt < 4; nt++) {
        const int col = 64 * hh + 16 * nt + l15;
        const int bof = col * 64 + (((4 * ks + l4) ^ (col & 7)) << 3);
        short8 bh = *(const short8*)(whb + bof);
        short8 bl = *(const short8*)(wlb + bof);
        acc[nt] = __builtin_amdgcn_mfma_f32_16x16x32_bf16(ah, bh, acc[nt], 0, 0, 0);
        acc[nt] = __builtin_amdgcn_mfma_f32_16x16x32_bf16(ah, bl, acc[nt], 0, 0, 0);
        acc[nt] = __builtin_amdgcn_mfma_f32_16x16x32_bf16(al, bh, acc[nt], 0, 0, 0);
      }
    }
    __syncthreads();
  }
#pragma unroll
  for (int nt = 0; nt < 4; nt++) {
    const int col = 64 * hh + 16 * nt + l15;
    const float bv = bias[col];
#pragma unroll
    for (int i = 0; i < 4; i++) {
      const int row = row0 + 16 * g + 4 * l4 + i;
      if (row < M) C[(size_t)row * 128 + col] = acc[nt][i] + bv;
    }
  }
}

// ---------------- counting sort of idx_ji ----------------
__global__ void hist_k(const int* __restrict__ ji, int* __restrict__ cnt, int T) {
  int t = blockIdx.x * 256 + threadIdx.x;
  const int stride = gridDim.x * 256;
  for (; t < T; t += stride) atomicAdd(&cnt[ji[t]], 1);
}

__global__ void scan1_k(const int* __restrict__ cnt, int* __restrict__ csum, int E) {
  __shared__ int red[256];
  const int c0 = blockIdx.x * 2048;
  int s = 0;
  for (int i = threadIdx.x; i < 2048; i += 256) {
    int e = c0 + i;
    if (e < E) s += cnt[e];
  }
  red[threadIdx.x] = s;
  __syncthreads();
  for (int o = 128; o > 0; o >>= 1) {
    if (threadIdx.x < o) red[threadIdx.x] += red[threadIdx.x + o];
    __syncthreads();
  }
  if (threadIdx.x == 0) csum[blockIdx.x] = red[0];
}

__global__ void scan2_k(int* __restrict__ csum, int n) {
  if (threadIdx.x == 0 && blockIdx.x == 0) {
    int acc = 0;
    for (int i = 0; i < n; i++) { int v = csum[i]; csum[i] = acc; acc += v; }
  }
}

__global__ void scan3_k(const int* __restrict__ cnt, const int* __restrict__ csum,
                        int* __restrict__ off, int E) {
  __shared__ int ts[256];
  const int c0 = blockIdx.x * 2048;
  const int tid = threadIdx.x;
  int loc[8];
  int s = 0;
#pragma unroll
  for (int k = 0; k < 8; k++) {
    int e = c0 + tid * 8 + k;
    loc[k] = (e < E) ? cnt[e] : 0;
    s += loc[k];
  }
  ts[tid] = s;
  __syncthreads();
  for (int o = 1; o < 256; o <<= 1) {
    int v = (tid >= o) ? ts[tid - o] : 0;
    __syncthreads();
    ts[tid] += v;
    __syncthreads();
  }
  int base = csum[blockIdx.x] + ((tid > 0) ? ts[tid - 1] : 0);
#pragma unroll
  for (int k = 0; k < 8; k++) {
    int e = c0 + tid * 8 + k;
    if (e < E) { off[e] = base; base += loc[k]; }
  }
}

__global__ void scatter_k(const int* __restrict__ ji, int* __restrict__ cursor,
                          int* __restrict__ perm, int T) {
  int t = blockIdx.x * 256 + threadIdx.x;
  const int stride = gridDim.x * 256;
  for (; t < T; t += stride) {
    int e = ji[t];
    int p = atomicAdd(&cursor[e], 1);
    perm[p] = t;
  }
}

// ---------------- fused triplet kernel (sorted order, 2-tile-deep prefetch) ----------------
struct G12 {
  short8 a0, a1;          // h[ki] 16 bf16
  short8 b0, b1;          // h[ji] 16 bf16
  float4 m0, m1, m2, m3;  // M row 16 f32
};

__device__ __forceinline__ void issue12(G12& g, const unsigned short* __restrict__ fa,
                                        const unsigned short* __restrict__ fb,
                                        const float* __restrict__ mm, int cseg)
{
  g.a0 = *(const short8*)(fa + cseg);
  g.a1 = *(const short8*)(fa + cseg + 8);
  g.b0 = *(const short8*)(fb + cseg);
  g.b1 = *(const short8*)(fb + cseg + 8);
  g.m0 = *(const float4*)(mm + cseg + 0);
  g.m1 = *(const float4*)(mm + cseg + 4);
  g.m2 = *(const float4*)(mm + cseg + 8);
  g.m3 = *(const float4*)(mm + cseg + 12);
}

__device__ __forceinline__ void pack8x(const short8& a, const short8& b,
                                       const float4& m0, const float4& m1, short8& o)
{
  float p[8];
  p[0] = bf2f((unsigned short)a[0]) * m0.x * bf2f((unsigned short)b[0]);
  p[1] = bf2f((unsigned short)a[1]) * m0.y * bf2f((unsigned short)b[1]);
  p[2] = bf2f((unsigned short)a[2]) * m0.z * bf2f((unsigned short)b[2]);
  p[3] = bf2f((unsigned short)a[3]) * m0.w * bf2f((unsigned short)b[3]);
  p[4] = bf2f((unsigned short)a[4]) * m1.x * bf2f((unsigned short)b[4]);
  p[5] = bf2f((unsigned short)a[5]) * m1.y * bf2f((unsigned short)b[5]);
  p[6] = bf2f((unsigned short)a[6]) * m1.z * bf2f((unsigned short)b[6]);
  p[7] = bf2f((unsigned short)a[7]) * m1.w * bf2f((unsigned short)b[7]);
  union { short8 s; unsigned u[4]; } t;
  t.u[0] = cvtpk_bf16(p[0], p[1]);
  t.u[1] = cvtpk_bf16(p[2], p[3]);
  t.u[2] = cvtpk_bf16(p[4], p[5]);
  t.u[3] = cvtpk_bf16(p[6], p[7]);
  o = t.s;
}

__device__ __forceinline__ void pack16(const G12& g, short8& lo, short8& hi)
{
  pack8x(g.a0, g.b0, g.m0, g.m1, lo);
  pack8x(g.a1, g.b1, g.m2, g.m3, hi);
}

__device__ __forceinline__ void writep(unsigned short* pb, int r, int cseg,
                                       const short8& lo, const short8& hi)
{
  const int c0 = cseg >> 3;
  *(short8*)(pb + r * 128 + (((c0) ^ (r & 7)) << 3)) = lo;
  *(short8*)(pb + r * 128 + (((c0 + 1) ^ (r & 7)) << 3)) = hi;
}

// A from pbA/pbB (chunk-XOR swizzle), B from fragment-order weight LDS:
// wF[((ctg*4 + ks)*64 + lane)*8 + j] = W[32*ks + 8*(lane>>4) + j][16*ctg + (lane&15)]
__device__ __forceinline__ void mfma_block4(const unsigned short* abuf,
                                            const unsigned short* wF,
                                            f32x4 (&acc)[4],
                                            int g, int hh, int lane, int l15, int l4)
{
  const int arow = 16 * g + l15;
  __builtin_amdgcn_s_setprio(1);
#pragma unroll
  for (int ks = 0; ks < 4; ks++) {
    short8 a = *(const short8*)(abuf + arow * 128 + (((4 * ks + l4) ^ (arow & 7)) << 3));
#pragma unroll
    for (int ct = 0; ct < 4; ct++) {
      const short8 b = *(const short8*)(wF + (((4 * hh + ct) * 4 + ks) * 64 + lane) * 8);
      acc[ct] = __builtin_amdgcn_mfma_f32_16x16x32_bf16(a, b, acc[ct], 0, 0, 0);
    }
  }
  __builtin_amdgcn_s_setprio(0);
}

__device__ __forceinline__ void store_s(unsigned short* pbuf, const f32x4 (&acc)[4],
                                        const float* __restrict__ bias,
                                        int g, int hh, int l15, int l4)
{
#pragma unroll
  for (int ct = 0; ct < 4; ct++) {
    const int col = 64 * hh + 16 * ct + l15;
    const float bv = bias[col];
#pragma unroll
    for (int i = 0; i < 4; i++) {
      const int r = 16 * g + 4 * l4 + i;
      float v = silu_f(acc[ct][i] + bv);
      pbuf[r * 128 + ((((col >> 3) ^ (r & 7)) << 3)) + (col & 7)] = f2bf(v);
    }
  }
}

// Assumes T % 64 == 0 (T = 1e6 -> 15625 tiles exactly).
__global__ __launch_bounds__(512, 2)
void triplet_fused(const unsigned short* __restrict__ h,
                   const float* __restrict__ M01, const float* __restrict__ M02,
                   const float* __restrict__ Ws01, const float* __restrict__ bs01,
                   const float* __restrict__ Ws02, const float* __restrict__ bs02,
                   const float* __restrict__ Ws,   const float* __restrict__ bs,
                   const int* __restrict__ idx_ji, const int* __restrict__ idx_ki,
                   const int* __restrict__ perm,
                   float* __restrict__ out_acc, int T)
{
  __shared__ unsigned short wF01[16384];   // 32 KB, fragment order
  __shared__ unsigned short wF02[16384];   // 32 KB
  __shared__ unsigned short wFA[16384];    // 32 KB (Ws rows 0..127)
  __shared__ unsigned short wFB[16384];    // 32 KB (Ws rows 128..255)
  __shared__ unsigned short pbA[64 * 128]; // 16 KB p-tiles
  __shared__ unsigned short pbB[64 * 128]; // 16 KB s-tiles

  const int tid = threadIdx.x;

  for (int e = tid; e < 16384; e += 512) {
    const int j = e & 7, ln = (e >> 3) & 63, ks = (e >> 9) & 3, ct = e >> 11;
    const int col = 16 * ct + (ln & 15);
    const int k = 32 * ks + 8 * (ln >> 4) + j;
    const int src = k * 128 + col;
    wF01[e] = f2bf(Ws01[src]);
    wF02[e] = f2bf(Ws02[src]);
    wFA[e]  = f2bf(Ws[src]);
    wFB[e]  = f2bf(Ws[16384 + src]);
  }
  __syncthreads();

  const int lane = tid & 63;
  const int wv = tid >> 6;
  const int g = wv & 3;        // row group (16 rows)
  const int hh = wv >> 2;      // col half (64 cols)
  const int l15 = lane & 15, l4 = lane >> 4;
  const f32x4 zero4 = {0.f, 0.f, 0.f, 0.f};

  float bsv[4];
#pragma unroll
  for (int ct = 0; ct < 4; ct++) bsv[ct] = bs[64 * hh + 16 * ct + l15];

  const int r = tid >> 3;           // gather row 0..63
  const int cseg = (tid & 7) * 16;  // 16 cols per thread
  const int ntiles = T >> 6;
  const int G = gridDim.x;

  int tile = blockIdx.x;
  if (tile >= ntiles) return;

  // clamped sorted-row index for tile q (prefetch rows past end read row T-1, unused)
  auto srow = [&](int q) { int s = q * 64 + r; return s < T ? s : T - 1; };

  // ---- prologue: 3-deep index chain + 2-deep gather pipeline ----
  int trow1, trow2, trow3;   // roles: t+1, t+2, (t+3 in-flight)
  int ek1, ej1, ek2, ej2;
  {
    const int trow0 = perm[srow(tile)];
    trow1 = perm[srow(tile + G)];
    trow2 = perm[srow(tile + 2 * G)];
    const int ek0 = idx_ki[trow0], ej0 = idx_ji[trow0];
    ek1 = idx_ki[trow1]; ej1 = idx_ji[trow1];
    ek2 = idx_ki[trow2]; ej2 = idx_ji[trow2];

    G12 gP;  // p01(t0) - packed immediately
    issue12(gP, h + (size_t)ek0 * 256, h + (size_t)ej0 * 256, M01 + (size_t)trow0 * 128, cseg);
    // start long-lived in-flight buffers via the loop-scope variables below
    trow3 = trow0;  // placeholder, overwritten each P2
    (void)gP;
    // p02(t0) + p01(t1) issued after gP so pack16(gP) waits minimal counters
    // (declared below, issued here)
    // NOTE: actual issue of g2/gB happens right after declarations.
    // pack p01(t0):
    // (done below after g2/gB issue to maximize overlap)
    // -- code continues below --
    // (gP consumed by pack16 into p01lo/hi)
    // placeholder block end
    short8 tmplo, tmphi;
    (void)tmplo; (void)tmphi;
    // real sequence continues outside this scope with gP alive
    // -- but C++ scoping: move everything into function scope instead:
    // (see below; gP re-declared at function scope)
  }

  // function-scope pipeline state
  G12 gA, gB, g2;
  short8 p01lo, p01hi;
  {
    const int trow0 = perm[srow(tile)];
    const int ek0 = idx_ki[trow0], ej0 = idx_ji[trow0];
    issue12(gA, h + (size_t)ek0 * 256, h + (size_t)ej0 * 256, M01 + (size_t)trow0 * 128, cseg);
    issue12(gB, h + (size_t)ek1 * 256, h + (size_t)ej1 * 256, M01 + (size_t)trow1 * 128, cseg);
    issue12(g2, h + (size_t)ek0 * 256 + 128, h + (size_t)ej0 * 256 + 128,
            M02 + (size_t)trow0 * 128, cseg);
    pack16(gA, p01lo, p01hi);   // waits gA only (oldest loads)
  }
  int parity = 0;  // 0: slot A free (P4 issues into A, P5 packs B)

  for (; tile < ntiles; tile += G) {
    // ---- P1: write p01(t) -> pbA ; load pj ----
    writep(pbA, r, cseg, p01lo, p01hi);
    const int pj = perm[(tile << 6) + 16 * g + l15];
    TSYNC();

    // ---- P2: MFMA1 -> s01 -> pbB ; load trow(t+3) ; jrv ----
    trow3 = perm[srow(tile + 3 * G)];
    const int jrv = idx_ji[pj];
    {
      f32x4 acc1[4] = {zero4, zero4, zero4, zero4};
      mfma_block4(pbA, wF01, acc1, g, hh, lane, l15, l4);
      store_s(pbB, acc1, bs01, g, hh, l15, l4);
    }
    TSYNC();

    // ---- P3: MFMA2 (s01,WsA)->acc3 ; pack p02(t) -> pbA ; re-issue g2 = p02(t+1) ----
    f32x4 acc3[4] = {zero4, zero4, zero4, zero4};
    mfma_block4(pbB, wFA, acc3, g, hh, lane, l15, l4);
    {
      short8 lo, hi;
      pack16(g2, lo, hi);
      writep(pbA, r, cseg, lo, hi);
    }
    issue12(g2, h + (size_t)ek1 * 256 + 128, h + (size_t)ej1 * 256 + 128,
            M02 + (size_t)trow1 * 128, cseg);
    TSYNC();

    // ---- P4: issue p01(t+2) into free slot ; MFMA3 -> s02 -> pbB ----
    if (parity == 0)
      issue12(gA, h + (size_t)ek2 * 256, h + (size_t)ej2 * 256, M01 + (size_t)trow2 * 128, cseg);
    else
      issue12(gB, h + (size_t)ek2 * 256, h + (size_t)ej2 * 256, M01 + (size_t)trow2 * 128, cseg);
    {
      f32x4 acc2[4] = {zero4, zero4, zero4, zero4};
      mfma_block4(pbA, wF02, acc2, g, hh, lane, l15, l4);
      store_s(pbB, acc2, bs02, g, hh, l15, l4);
    }
    TSYNC();

    // ---- P5: MFMA4 ; load idx(t+3) ; segsum ; pack p01(t+1) ; shift chain ----
    mfma_block4(pbB, wFB, acc3, g, hh, lane, l15, l4);
    const int ek3 = idx_ki[trow3], ej3 = idx_ji[trow3];
    {
      float sf[4][4];
#pragma unroll
      for (int ct = 0; ct < 4; ct++)
#pragma unroll
        for (int i = 0; i < 4; i++)
          sf[ct][i] = silu_f(acc3[ct][i] + bsv[ct]);

      const int ejp = __shfl_up(jrv, 1, 16);
      unsigned bm = (unsigned)(__ballot((l15 > 0) && (jrv != ejp)) & 0xFFFFull);
      int fr = 0;
      unsigned rem = bm;
      while (fr < 16) {
        const int nxt = rem ? (__ffs(rem) - 1) : 16;
        rem &= rem - 1;
        const int lr = nxt - 1;
        const int e = __shfl(jrv, fr, 16);
        float sv[4];
#pragma unroll
        for (int ct = 0; ct < 4; ct++) {
          float s = 0.f;
#pragma unroll
          for (int i = 0; i < 4; i++) {
            const int rr = 4 * l4 + i;
            s += (rr >= fr && rr <= lr) ? sf[ct][i] : 0.f;
          }
          s += __shfl_xor(s, 16);
          s += __shfl_xor(s, 32);
          sv[ct] = s;
        }
        const float s0 = (l4 == 0) ? sv[0] : (l4 == 1) ? sv[1] : (l4 == 2) ? sv[2] : sv[3];
        float* dst = out_acc + (size_t)e * 128 + 64 * hh + 16 * l4 + l15;
        if (fr == 0 || lr == 15) atomicAdd(dst, s0);  // run may continue outside subwindow
        else *dst = s0;                               // strictly interior -> exclusive
        fr = nxt;
      }
    }
    if (parity == 0) pack16(gB, p01lo, p01hi);   // p01(t+1) was in slot B
    else             pack16(gA, p01lo, p01hi);
    parity ^= 1;
    ek1 = ek2; ej1 = ej2; trow1 = trow2;
    ek2 = ek3; ej2 = ej3; trow2 = trow3;
    TSYNC();  // pbB reads (MFMA4) done before next tile's P2 writes
  }
}

extern "C" void kernel_launch(void* const* d_in, const int* in_sizes, int n_in,
                              void* d_out, int out_size, void* d_ws, size_t ws_size,
                              hipStream_t stream)
{
  const float* f    = (const float*)d_in[0];
  const float* M01  = (const float*)d_in[1];
  const float* M02  = (const float*)d_in[2];
  const float* W1   = (const float*)d_in[3];
  const float* b1   = (const float*)d_in[4];
  const float* W2   = (const float*)d_in[5];
  const float* b2   = (const float*)d_in[6];
  const float* Ws01 = (const float*)d_in[7];
  const float* bs01 = (const float*)d_in[8];
  const float* Ws02 = (const float*)d_in[9];
  const float* bs02 = (const float*)d_in[10];
  const float* Ws   = (const float*)d_in[11];
  const float* bs   = (const float*)d_in[12];
  const float* Wout = (const float*)d_in[13];
  const float* bout = (const float*)d_in[14];
  const int* idx_ji = (const int*)d_in[16];
  const int* idx_ki = (const int*)d_in[17];

  const int E = in_sizes[0] / 256;
  const int T = in_sizes[1] / 128;

  char* w = (char*)d_ws;
  unsigned short* hbuf = (unsigned short*)w;                       // [E][256] bf16
  size_t o = ((size_t)E * 256 * 2 + 255) & ~(size_t)255;
  unsigned short* wt1h = (unsigned short*)(w + o); o += 256 * 256 * 2;
  unsigned short* wt1l = (unsigned short*)(w + o); o += 256 * 256 * 2;
  unsigned short* wt2h = (unsigned short*)(w + o); o += 256 * 256 * 2;
  unsigned short* wt2l = (unsigned short*)(w + o); o += 256 * 256 * 2;
  unsigned short* wtoh = (unsigned short*)(w + o); o += 128 * 128 * 2;
  unsigned short* wtol = (unsigned short*)(w + o); o += 128 * 128 * 2;
  o = (o + 255) & ~(size_t)255;
  int* cnt = (int*)(w + o);  o += ((size_t)E * 4 + 255) & ~(size_t)255;
  int* off = (int*)(w + o);  o += ((size_t)E * 4 + 255) & ~(size_t)255;
  int* csum = (int*)(w + o); o += 4096;
  int* perm = (int*)(w + o);                                       // [T]

  float* out_acc = (float*)d_out;
  const int mb = (E + 63) / 64;

  prep_all<<<(256 * 256 + 255) / 256, 256, 0, stream>>>(W1, wt1h, wt1l,
                                                        W2, wt2h, wt2l,
                                                        Wout, wtoh, wtol);

  mlp_gemm<0, 1><<<mb, 512, 0, stream>>>(f, wt1h, wt1l, b1, hbuf, E);
  mlp_gemm<1, 0><<<mb, 512, 0, stream>>>(hbuf, wt2h, wt2l, b2, hbuf, E);

  hipMemsetAsync(cnt, 0, (size_t)E * 4, stream);
  hist_k<<<1024, 256, 0, stream>>>(idx_ji, cnt, T);
  const int nchunks = (E + 2047) / 2048;
  scan1_k<<<nchunks, 256, 0, stream>>>(cnt, csum, E);
  scan2_k<<<1, 64, 0, stream>>>(csum, nchunks);
  scan3_k<<<nchunks, 256, 0, stream>>>(cnt, csum, off, E);
  scatter_k<<<1024, 256, 0, stream>>>(idx_ji, off, perm, T);

  hipMemsetAsync(d_out, 0, (size_t)E * 128 * sizeof(float), stream);

  const int ntiles = (T + 63) / 64;
  const int grid = ntiles < 256 ? ntiles : 256;  // persistent, 1 block/CU
  triplet_fused<<<grid, 512, 0, stream>>>(hbuf, M01, M02, Ws01, bs01, Ws02, bs02,
                                          Ws, bs, idx_ji, idx_ki, perm, out_acc, T);

  final_gemm<<<mb, 512, 0, stream>>>(out_acc, wtoh, wtol, bout, out_acc, E);
}

// Round 9
// 818.765 us; speedup vs baseline: 1.6856x; 1.1490x over previous
//
#include <hip/hip_runtime.h>

typedef __attribute__((ext_vector_type(8))) short short8;
typedef __attribute__((ext_vector_type(4))) float f32x4;

__device__ __forceinline__ float silu_f(float x) { return x / (1.0f + __expf(-x)); }

__device__ __forceinline__ unsigned short f2bf(float x) {
  unsigned u = __float_as_uint(x);
  u += 0x7FFFu + ((u >> 16) & 1u);
  return (unsigned short)(u >> 16);
}
__device__ __forceinline__ float bf2f(unsigned short v) {
  return __uint_as_float(((unsigned)v) << 16);
}
__device__ __forceinline__ unsigned cvtpk_bf16(float lo, float hi) {
  unsigned r;
  asm("v_cvt_pk_bf16_f32 %0, %1, %2" : "=v"(r) : "v"(lo), "v"(hi));
  return r;
}

// same-wave LDS write->read fence (no inter-wave barrier); sched_barrier per rule #18
#define LGKM_SB() do { asm volatile("s_waitcnt lgkmcnt(0)" ::: "memory"); \
                       __builtin_amdgcn_sched_barrier(0); } while (0)

// ---------------- weight prep (fused): W[K][N] f32 -> panel-swizzled bf16 hi/lo ----------------
__device__ __forceinline__ void prep_one(const float* __restrict__ W,
                                         unsigned short* __restrict__ wh,
                                         unsigned short* __restrict__ wl,
                                         int N, int e)
{
  int k = e / N, n = e % N;
  float w = W[e];
  unsigned short hi = f2bf(w);
  unsigned short lo = f2bf(w - bf2f(hi));
  int kp = k >> 6, kk = k & 63;
  size_t dst = (size_t)kp * N * 64 + (size_t)n * 64 + ((((kk >> 3) ^ (n & 7)) << 3)) + (kk & 7);
  wh[dst] = hi;
  wl[dst] = lo;
}

__global__ void prep_all(const float* __restrict__ W1, unsigned short* w1h, unsigned short* w1l,
                         const float* __restrict__ W2, unsigned short* w2h, unsigned short* w2l,
                         const float* __restrict__ Wo, unsigned short* woh, unsigned short* wol)
{
  int e = blockIdx.x * 256 + threadIdx.x;
  if (e < 256 * 256) {
    prep_one(W1, w1h, w1l, 256, e);
    prep_one(W2, w2h, w2l, 256, e);
  }
  if (e < 128 * 128) prep_one(Wo, woh, wol, 128, e);
}

// ---------------- MLP GEMM: C = silu(A @ W + b), K=256, N=256, bf16 out ----------------
template<int INBF, int ASPLIT>
__global__ __launch_bounds__(512)
void mlp_gemm(const void* A_, const unsigned short* __restrict__ wh,
              const unsigned short* __restrict__ wl,
              const float* __restrict__ bias, unsigned short* __restrict__ C, int M)
{
  __shared__ unsigned short aTh[64 * 64], aTl[64 * 64];
  __shared__ unsigned short whb[256 * 64], wlb[256 * 64];
  const int tid = threadIdx.x;
  const int lane = tid & 63, wv = tid >> 6;
  const int g = wv & 3, hh = wv >> 2;
  const int l15 = lane & 15, l4 = lane >> 4;
  const int row0 = blockIdx.x * 64;
  const int r = tid >> 3, kseg = (tid & 7) * 8;
  const f32x4 zero4 = {0.f, 0.f, 0.f, 0.f};

  f32x4 acc[8];
#pragma unroll
  for (int nt = 0; nt < 8; nt++) acc[nt] = zero4;

  for (int kp = 0; kp < 4; kp++) {
    {
      const int grow = row0 + r;
      float x[8];
      if (grow < M) {
        if (INBF) {
          short8 v = *(const short8*)((const unsigned short*)A_ + (size_t)grow * 256 + kp * 64 + kseg);
#pragma unroll
          for (int j = 0; j < 8; j++) x[j] = bf2f((unsigned short)v[j]);
        } else {
          const float* ap = (const float*)A_ + (size_t)grow * 256 + kp * 64 + kseg;
          float4 v0 = *(const float4*)ap;
          float4 v1 = *(const float4*)(ap + 4);
          x[0] = v0.x; x[1] = v0.y; x[2] = v0.z; x[3] = v0.w;
          x[4] = v1.x; x[5] = v1.y; x[6] = v1.z; x[7] = v1.w;
        }
      } else {
#pragma unroll
        for (int j = 0; j < 8; j++) x[j] = 0.f;
      }
      union { short8 s; unsigned short us[8]; } H, L;
#pragma unroll
      for (int j = 0; j < 8; j++) {
        H.us[j] = f2bf(x[j]);
        L.us[j] = ASPLIT ? f2bf(x[j] - bf2f(H.us[j])) : (unsigned short)0;
      }
      const int dst = r * 64 + ((((kseg >> 3) ^ (r & 7)) << 3));
      *(short8*)(aTh + dst) = H.s;
      if (ASPLIT) *(short8*)(aTl + dst) = L.s;
    }
    {
      const short8* srcH = (const short8*)(wh + (size_t)kp * 16384);
      const short8* srcL = (const short8*)(wl + (size_t)kp * 16384);
#pragma unroll
      for (int i = 0; i < 4; i++) {
        ((short8*)whb)[tid + 512 * i] = srcH[tid + 512 * i];
        ((short8*)wlb)[tid + 512 * i] = srcL[tid + 512 * i];
      }
    }
    __syncthreads();
#pragma unroll
    for (int ks = 0; ks < 2; ks++) {
      const int arow = 16 * g + l15;
      const int aof = arow * 64 + (((4 * ks + l4) ^ (arow & 7)) << 3);
      short8 ah = *(const short8*)(aTh + aof);
      short8 al = *(const short8*)(aTl + aof);
#pragma unroll
      for (int nt = 0; nt < 8; nt++) {
        const int col = 128 * hh + 16 * nt + l15;
        const int bof = col * 64 + (((4 * ks + l4) ^ (col & 7)) << 3);
        short8 bh = *(const short8*)(whb + bof);
        short8 bl = *(const short8*)(wlb + bof);
        acc[nt] = __builtin_amdgcn_mfma_f32_16x16x32_bf16(ah, bh, acc[nt], 0, 0, 0);
        acc[nt] = __builtin_amdgcn_mfma_f32_16x16x32_bf16(ah, bl, acc[nt], 0, 0, 0);
        if (ASPLIT)
          acc[nt] = __builtin_amdgcn_mfma_f32_16x16x32_bf16(al, bh, acc[nt], 0, 0, 0);
      }
    }
    __syncthreads();
  }
#pragma unroll
  for (int nt = 0; nt < 8; nt++) {
    const int col = 128 * hh + 16 * nt + l15;
    const float bv = bias[col];
#pragma unroll
    for (int i = 0; i < 4; i++) {
      const int row = row0 + 16 * g + 4 * l4 + i;
      if (row < M) C[(size_t)row * 256 + col] = f2bf(silu_f(acc[nt][i] + bv));
    }
  }
}

// ---------------- final GEMM: C = A @ Wout + b, K=128, N=128, f32 in/out ----------------
__global__ __launch_bounds__(512)
void final_gemm(const float* __restrict__ A, const unsigned short* __restrict__ wh,
                const unsigned short* __restrict__ wl,
                const float* __restrict__ bias, float* __restrict__ C, int M)
{
  __shared__ unsigned short aTh[64 * 64], aTl[64 * 64];
  __shared__ unsigned short whb[128 * 64], wlb[128 * 64];
  const int tid = threadIdx.x;
  const int lane = tid & 63, wv = tid >> 6;
  const int g = wv & 3, hh = wv >> 2;
  const int l15 = lane & 15, l4 = lane >> 4;
  const int row0 = blockIdx.x * 64;
  const int r = tid >> 3, kseg = (tid & 7) * 8;
  const f32x4 zero4 = {0.f, 0.f, 0.f, 0.f};

  f32x4 acc[4];
#pragma unroll
  for (int nt = 0; nt < 4; nt++) acc[nt] = zero4;

  for (int kp = 0; kp < 2; kp++) {
    {
      const int grow = row0 + r;
      float x[8];
      if (grow < M) {
        const float* ap = A + (size_t)grow * 128 + kp * 64 + kseg;
        float4 v0 = *(const float4*)ap;
        float4 v1 = *(const float4*)(ap + 4);
        x[0] = v0.x; x[1] = v0.y; x[2] = v0.z; x[3] = v0.w;
        x[4] = v1.x; x[5] = v1.y; x[6] = v1.z; x[7] = v1.w;
      } else {
#pragma unroll
        for (int j = 0; j < 8; j++) x[j] = 0.f;
      }
      union { short8 s; unsigned short us[8]; } H, L;
#pragma unroll
      for (int j = 0; j < 8; j++) {
        H.us[j] = f2bf(x[j]);
        L.us[j] = f2bf(x[j] - bf2f(H.us[j]));
      }
      const int dst = r * 64 + ((((kseg >> 3) ^ (r & 7)) << 3));
      *(short8*)(aTh + dst) = H.s;
      *(short8*)(aTl + dst) = L.s;
    }
    {
      const short8* srcH = (const short8*)(wh + (size_t)kp * 8192);
      const short8* srcL = (const short8*)(wl + (size_t)kp * 8192);
#pragma unroll
      for (int i = 0; i < 2; i++) {
        ((short8*)whb)[tid + 512 * i] = srcH[tid + 512 * i];
        ((short8*)wlb)[tid + 512 * i] = srcL[tid + 512 * i];
      }
    }
    __syncthreads();
#pragma unroll
    for (int ks = 0; ks < 2; ks++) {
      const int arow = 16 * g + l15;
      const int aof = arow * 64 + (((4 * ks + l4) ^ (arow & 7)) << 3);
      short8 ah = *(const short8*)(aTh + aof);
      short8 al = *(const short8*)(aTl + aof);
#pragma unroll
      for (int nt = 0; nt < 4; nt++) {
        const int col = 64 * hh + 16 * nt + l15;
        const int bof = col * 64 + (((4 * ks + l4) ^ (col & 7)) << 3);
        short8 bh = *(const short8*)(whb + bof);
        short8 bl = *(const short8*)(wlb + bof);
        acc[nt] = __builtin_amdgcn_mfma_f32_16x16x32_bf16(ah, bh, acc[nt], 0, 0, 0);
        acc[nt] = __builtin_amdgcn_mfma_f32_16x16x32_bf16(ah, bl, acc[nt], 0, 0, 0);
        acc[nt] = __builtin_amdgcn_mfma_f32_16x16x32_bf16(al, bh, acc[nt], 0, 0, 0);
      }
    }
    __syncthreads();
  }
#pragma unroll
  for (int nt = 0; nt < 4; nt++) {
    const int col = 64 * hh + 16 * nt + l15;
    const float bv = bias[col];
#pragma unroll
    for (int i = 0; i < 4; i++) {
      const int row = row0 + 16 * g + 4 * l4 + i;
      if (row < M) C[(size_t)row * 128 + col] = acc[nt][i] + bv;
    }
  }
}

// ---------------- counting sort of idx_ji ----------------
__global__ void hist_k(const int* __restrict__ ji, int* __restrict__ cnt, int T) {
  int t = blockIdx.x * 256 + threadIdx.x;
  const int stride = gridDim.x * 256;
  for (; t < T; t += stride) atomicAdd(&cnt[ji[t]], 1);
}

__global__ void scan1_k(const int* __restrict__ cnt, int* __restrict__ csum, int E) {
  __shared__ int red[256];
  const int c0 = blockIdx.x * 2048;
  int s = 0;
  for (int i = threadIdx.x; i < 2048; i += 256) {
    int e = c0 + i;
    if (e < E) s += cnt[e];
  }
  red[threadIdx.x] = s;
  __syncthreads();
  for (int o = 128; o > 0; o >>= 1) {
    if (threadIdx.x < o) red[threadIdx.x] += red[threadIdx.x + o];
    __syncthreads();
  }
  if (threadIdx.x == 0) csum[blockIdx.x] = red[0];
}

__global__ void scan2_k(int* __restrict__ csum, int n) {
  if (threadIdx.x == 0 && blockIdx.x == 0) {
    int acc = 0;
    for (int i = 0; i < n; i++) { int v = csum[i]; csum[i] = acc; acc += v; }
  }
}

__global__ void scan3_k(const int* __restrict__ cnt, const int* __restrict__ csum,
                        int* __restrict__ off, int E) {
  __shared__ int ts[256];
  const int c0 = blockIdx.x * 2048;
  const int tid = threadIdx.x;
  int loc[8];
  int s = 0;
#pragma unroll
  for (int k = 0; k < 8; k++) {
    int e = c0 + tid * 8 + k;
    loc[k] = (e < E) ? cnt[e] : 0;
    s += loc[k];
  }
  ts[tid] = s;
  __syncthreads();
  for (int o = 1; o < 256; o <<= 1) {
    int v = (tid >= o) ? ts[tid - o] : 0;
    __syncthreads();
    ts[tid] += v;
    __syncthreads();
  }
  int base = csum[blockIdx.x] + ((tid > 0) ? ts[tid - 1] : 0);
#pragma unroll
  for (int k = 0; k < 8; k++) {
    int e = c0 + tid * 8 + k;
    if (e < E) { off[e] = base; base += loc[k]; }
  }
}

__global__ void scatter_k(const int* __restrict__ ji, int* __restrict__ cursor,
                          int* __restrict__ perm, int T) {
  int t = blockIdx.x * 256 + threadIdx.x;
  const int stride = gridDim.x * 256;
  for (; t < T; t += stride) {
    int e = ji[t];
    int p = atomicAdd(&cursor[e], 1);
    perm[p] = t;
  }
}

// ---------------- fused triplet kernel: wave-independent 16-row subwindows ----------------
__device__ __forceinline__ short8 pack8p(const short8 a, const short8 b,
                                         const float4 m0, const float4 m1)
{
  float p0 = bf2f((unsigned short)a[0]) * m0.x * bf2f((unsigned short)b[0]);
  float p1 = bf2f((unsigned short)a[1]) * m0.y * bf2f((unsigned short)b[1]);
  float p2 = bf2f((unsigned short)a[2]) * m0.z * bf2f((unsigned short)b[2]);
  float p3 = bf2f((unsigned short)a[3]) * m0.w * bf2f((unsigned short)b[3]);
  float p4 = bf2f((unsigned short)a[4]) * m1.x * bf2f((unsigned short)b[4]);
  float p5 = bf2f((unsigned short)a[5]) * m1.y * bf2f((unsigned short)b[5]);
  float p6 = bf2f((unsigned short)a[6]) * m1.z * bf2f((unsigned short)b[6]);
  float p7 = bf2f((unsigned short)a[7]) * m1.w * bf2f((unsigned short)b[7]);
  union { short8 s; unsigned u[4]; } t;
  t.u[0] = cvtpk_bf16(p0, p1);
  t.u[1] = cvtpk_bf16(p2, p3);
  t.u[2] = cvtpk_bf16(p4, p5);
  t.u[3] = cvtpk_bf16(p6, p7);
  return t.s;
}

// Requires T % 16 == 0 (T = 1e6 -> 62500 subwindows of 16 sorted rows).
__global__ __launch_bounds__(512, 2)
void triplet_fused(const unsigned short* __restrict__ h,
                   const float* __restrict__ M01, const float* __restrict__ M02,
                   const float* __restrict__ Ws01, const float* __restrict__ bs01,
                   const float* __restrict__ Ws02, const float* __restrict__ bs02,
                   const float* __restrict__ Ws,   const float* __restrict__ bs,
                   const int* __restrict__ idx_ji, const int* __restrict__ idx_ki,
                   const int* __restrict__ perm,
                   float* __restrict__ out_acc, int T)
{
  // weights in MFMA-fragment order: elem((ct*4+ks)*64 + lane)*8 + j -> conflict-free B reads
  __shared__ unsigned short wF01[16384];   // 32 KB
  __shared__ unsigned short wF02[16384];   // 32 KB
  __shared__ unsigned short wFA[16384];    // 32 KB (Ws rows 0..127)
  __shared__ unsigned short wFB[16384];    // 32 KB (Ws rows 128..255)
  __shared__ unsigned short sbuf[8][2048]; // 4 KB per wave (16 rows x 128 cols bf16)

  const int tid = threadIdx.x;
  for (int e = tid; e < 16384; e += 512) {
    const int j = e & 7, ln = (e >> 3) & 63, ks = (e >> 9) & 3, ct = e >> 11;
    const int col = 16 * ct + (ln & 15);
    const int k = 32 * ks + 8 * (ln >> 4) + j;
    const int src = k * 128 + col;
    wF01[e] = f2bf(Ws01[src]);
    wF02[e] = f2bf(Ws02[src]);
    wFA[e]  = f2bf(Ws[src]);
    wFB[e]  = f2bf(Ws[16384 + src]);
  }
  __syncthreads();  // only barrier in the kernel

  const int lane = tid & 63, wv = tid >> 6;
  const int l15 = lane & 15, l4 = lane >> 4;
  unsigned short* const sb = sbuf[wv];
  const f32x4 zero4 = {0.f, 0.f, 0.f, 0.f};

  float bs01v[8], bs02v[8], bsv[8];
#pragma unroll
  for (int ct = 0; ct < 8; ct++) {
    bs01v[ct] = bs01[16 * ct + l15];
    bs02v[ct] = bs02[16 * ct + l15];
    bsv[ct]   = bs[16 * ct + l15];
  }

  const int nsub = T >> 4;
  const int stride = gridDim.x * 8;
  int sub = blockIdx.x * 8 + wv;

  // prologue: first subwindow's indices
  int pidx = perm[(sub << 4) + l15];
  int ek = idx_ki[pidx], ej = idx_ji[pidx];

  for (; sub < nsub; sub += stride) {
    // ---- issue ALL gathers for this subwindow (per-lane row l15, k-slices 8*l4) ----
    const unsigned short* fa = h + (size_t)ek * 256 + 8 * l4;
    const unsigned short* fb = h + (size_t)ej * 256 + 8 * l4;
    const float* mm1 = M01 + (size_t)pidx * 128 + 8 * l4;
    const float* mm2 = M02 + (size_t)pidx * 128 + 8 * l4;
    short8 ra1[4], rb1[4], ra2[4], rb2[4];
    float4 rm1[8], rm2[8];
#pragma unroll
    for (int ks = 0; ks < 4; ks++) {
      ra1[ks] = *(const short8*)(fa + 32 * ks);
      rb1[ks] = *(const short8*)(fb + 32 * ks);
      rm1[2 * ks]     = *(const float4*)(mm1 + 32 * ks);
      rm1[2 * ks + 1] = *(const float4*)(mm1 + 32 * ks + 4);
      ra2[ks] = *(const short8*)(fa + 128 + 32 * ks);
      rb2[ks] = *(const short8*)(fb + 128 + 32 * ks);
      rm2[2 * ks]     = *(const float4*)(mm2 + 32 * ks);
      rm2[2 * ks + 1] = *(const float4*)(mm2 + 32 * ks + 4);
    }

    // prefetch next subwindow's perm entry (dependent idx loads issued mid-body)
    const int subn = sub + stride;
    int sidx = (subn << 4) + l15;
    if (sidx >= T) sidx = T - 1;             // clamp; values unused past end
    const int pidx_n = perm[sidx];

    // ---- MFMA1: p01 @ Ws01 -> acc1[8] (16 rows x 128 cols) ----
    f32x4 acc1[8];
#pragma unroll
    for (int ct = 0; ct < 8; ct++) acc1[ct] = zero4;
#pragma unroll
    for (int ks = 0; ks < 4; ks++) {
      const short8 a = pack8p(ra1[ks], rb1[ks], rm1[2 * ks], rm1[2 * ks + 1]);
#pragma unroll
      for (int ct = 0; ct < 8; ct++) {
        const short8 b = *(const short8*)(wF01 + ((ct * 4 + ks) * 64 + lane) * 8);
        acc1[ct] = __builtin_amdgcn_mfma_f32_16x16x32_bf16(a, b, acc1[ct], 0, 0, 0);
      }
    }

    // ---- s01 = silu(acc1+bs01) -> wave-private sbuf (chunk-XOR swizzle) ----
#pragma unroll
    for (int ct = 0; ct < 8; ct++) {
      const int chi = 2 * ct + (l15 >> 3);
#pragma unroll
      for (int i = 0; i < 4; i++) {
        const int row = 4 * l4 + i;
        sb[row * 128 + (((chi ^ (row & 7)) << 3)) + (l15 & 7)] =
            f2bf(silu_f(acc1[ct][i] + bs01v[ct]));
      }
    }
    LGKM_SB();
    short8 as1[4];
#pragma unroll
    for (int ks = 0; ks < 4; ks++)
      as1[ks] = *(const short8*)(sb + l15 * 128 + (((4 * ks + l4) ^ (l15 & 7)) << 3));

    // ---- MFMA2: s01 @ WsA -> acc3[8] ----
    f32x4 acc3[8];
#pragma unroll
    for (int ct = 0; ct < 8; ct++) acc3[ct] = zero4;
#pragma unroll
    for (int ks = 0; ks < 4; ks++)
#pragma unroll
      for (int ct = 0; ct < 8; ct++) {
        const short8 b = *(const short8*)(wFA + ((ct * 4 + ks) * 64 + lane) * 8);
        acc3[ct] = __builtin_amdgcn_mfma_f32_16x16x32_bf16(as1[ks], b, acc3[ct], 0, 0, 0);
      }

    // next-subwindow dependent idx loads (covered by MFMA3..4)
    const int ekn = idx_ki[pidx_n], ejn = idx_ji[pidx_n];

    // ---- MFMA3: p02 @ Ws02 -> acc1 (reuse) ----
#pragma unroll
    for (int ct = 0; ct < 8; ct++) acc1[ct] = zero4;
#pragma unroll
    for (int ks = 0; ks < 4; ks++) {
      const short8 a = pack8p(ra2[ks], rb2[ks], rm2[2 * ks], rm2[2 * ks + 1]);
#pragma unroll
      for (int ct = 0; ct < 8; ct++) {
        const short8 b = *(const short8*)(wF02 + ((ct * 4 + ks) * 64 + lane) * 8);
        acc1[ct] = __builtin_amdgcn_mfma_f32_16x16x32_bf16(a, b, acc1[ct], 0, 0, 0);
      }
    }

    // ---- s02 -> sbuf (as1 already consumed; wave-private, no WAR hazard) ----
#pragma unroll
    for (int ct = 0; ct < 8; ct++) {
      const int chi = 2 * ct + (l15 >> 3);
#pragma unroll
      for (int i = 0; i < 4; i++) {
        const int row = 4 * l4 + i;
        sb[row * 128 + (((chi ^ (row & 7)) << 3)) + (l15 & 7)] =
            f2bf(silu_f(acc1[ct][i] + bs02v[ct]));
      }
    }
    LGKM_SB();
    short8 as2[4];
#pragma unroll
    for (int ks = 0; ks < 4; ks++)
      as2[ks] = *(const short8*)(sb + l15 * 128 + (((4 * ks + l4) ^ (l15 & 7)) << 3));

    // ---- MFMA4: s02 @ WsB -> acc3 += ----
#pragma unroll
    for (int ks = 0; ks < 4; ks++)
#pragma unroll
      for (int ct = 0; ct < 8; ct++) {
        const short8 b = *(const short8*)(wFB + ((ct * 4 + ks) * 64 + lane) * 8);
        acc3[ct] = __builtin_amdgcn_mfma_f32_16x16x32_bf16(as2[ks], b, acc3[ct], 0, 0, 0);
      }

    // ---- sfin = silu(acc3 + bs) in place ----
#pragma unroll
    for (int ct = 0; ct < 8; ct++)
#pragma unroll
      for (int i = 0; i < 4; i++)
        acc3[ct][i] = silu_f(acc3[ct][i] + bsv[ct]);

    // ---- register segment-sum over 16 sorted rows (round-8 proven logic, full 128 cols) ----
    {
      const int ejp = __shfl_up(ej, 1, 16);
      unsigned bm = (unsigned)(__ballot((l15 > 0) && (ej != ejp)) & 0xFFFFull);
      int fr = 0;
      unsigned rem = bm;
      while (fr < 16) {
        const int nxt = rem ? (__ffs(rem) - 1) : 16;
        rem &= rem - 1;
        const int lr = nxt - 1;
        const int e = __shfl(ej, fr, 16);
        float sv[8];
#pragma unroll
        for (int ct = 0; ct < 8; ct++) {
          float s = 0.f;
#pragma unroll
          for (int i = 0; i < 4; i++) {
            const int rr = 4 * l4 + i;
            s += (rr >= fr && rr <= lr) ? acc3[ct][i] : 0.f;
          }
          s += __shfl_xor(s, 16);
          s += __shfl_xor(s, 32);
          sv[ct] = s;
        }
        float w0, w1;
        if (l4 == 0)      { w0 = sv[0]; w1 = sv[1]; }
        else if (l4 == 1) { w0 = sv[2]; w1 = sv[3]; }
        else if (l4 == 2) { w0 = sv[4]; w1 = sv[5]; }
        else              { w0 = sv[6]; w1 = sv[7]; }
        float* dst = out_acc + (size_t)e * 128 + 32 * l4 + l15;
        if (fr == 0 || lr == 15) {   // run may continue into adjacent subwindow
          atomicAdd(dst, w0);
          atomicAdd(dst + 16, w1);
        } else {                     // strictly interior -> exclusive
          dst[0] = w0;
          dst[16] = w1;
        }
        fr = nxt;
      }
    }

    pidx = pidx_n; ek = ekn; ej = ejn;
  }
}

extern "C" void kernel_launch(void* const* d_in, const int* in_sizes, int n_in,
                              void* d_out, int out_size, void* d_ws, size_t ws_size,
                              hipStream_t stream)
{
  const float* f    = (const float*)d_in[0];
  const float* M01  = (const float*)d_in[1];
  const float* M02  = (const float*)d_in[2];
  const float* W1   = (const float*)d_in[3];
  const float* b1   = (const float*)d_in[4];
  const float* W2   = (const float*)d_in[5];
  const float* b2   = (const float*)d_in[6];
  const float* Ws01 = (const float*)d_in[7];
  const float* bs01 = (const float*)d_in[8];
  const float* Ws02 = (const float*)d_in[9];
  const float* bs02 = (const float*)d_in[10];
  const float* Ws   = (const float*)d_in[11];
  const float* bs   = (const float*)d_in[12];
  const float* Wout = (const float*)d_in[13];
  const float* bout = (const float*)d_in[14];
  const int* idx_ji = (const int*)d_in[16];
  const int* idx_ki = (const int*)d_in[17];

  const int E = in_sizes[0] / 256;
  const int T = in_sizes[1] / 128;

  char* w = (char*)d_ws;
  unsigned short* hbuf = (unsigned short*)w;                       // [E][256] bf16
  size_t o = ((size_t)E * 256 * 2 + 255) & ~(size_t)255;
  unsigned short* wt1h = (unsigned short*)(w + o); o += 256 * 256 * 2;
  unsigned short* wt1l = (unsigned short*)(w + o); o += 256 * 256 * 2;
  unsigned short* wt2h = (unsigned short*)(w + o); o += 256 * 256 * 2;
  unsigned short* wt2l = (unsigned short*)(w + o); o += 256 * 256 * 2;
  unsigned short* wtoh = (unsigned short*)(w + o); o += 128 * 128 * 2;
  unsigned short* wtol = (unsigned short*)(w + o); o += 128 * 128 * 2;
  o = (o + 255) & ~(size_t)255;
  int* cnt = (int*)(w + o);  o += ((size_t)E * 4 + 255) & ~(size_t)255;
  int* off = (int*)(w + o);  o += ((size_t)E * 4 + 255) & ~(size_t)255;
  int* csum = (int*)(w + o); o += 4096;
  int* perm = (int*)(w + o);                                       // [T]

  float* out_acc = (float*)d_out;
  const int mb = (E + 63) / 64;

  prep_all<<<(256 * 256 + 255) / 256, 256, 0, stream>>>(W1, wt1h, wt1l,
                                                        W2, wt2h, wt2l,
                                                        Wout, wtoh, wtol);

  mlp_gemm<0, 1><<<mb, 512, 0, stream>>>(f, wt1h, wt1l, b1, hbuf, E);
  mlp_gemm<1, 0><<<mb, 512, 0, stream>>>(hbuf, wt2h, wt2l, b2, hbuf, E);

  hipMemsetAsync(cnt, 0, (size_t)E * 4, stream);
  hist_k<<<1024, 256, 0, stream>>>(idx_ji, cnt, T);
  const int nchunks = (E + 2047) / 2048;
  scan1_k<<<nchunks, 256, 0, stream>>>(cnt, csum, E);
  scan2_k<<<1, 64, 0, stream>>>(csum, nchunks);
  scan3_k<<<nchunks, 256, 0, stream>>>(cnt, csum, off, E);
  scatter_k<<<1024, 256, 0, stream>>>(idx_ji, off, perm, T);

  hipMemsetAsync(d_out, 0, (size_t)E * 128 * sizeof(float), stream);

  triplet_fused<<<256, 512, 0, stream>>>(hbuf, M01, M02, Ws01, bs01, Ws02, bs02,
                                         Ws, bs, idx_ji, idx_ki, perm, out_acc, T);

  final_gemm<<<mb, 512, 0, stream>>>(out_acc, wtoh, wtol, bout, out_acc, E);
}